// Round 8
// baseline (606.647 us; speedup 1.0000x reference)
//
#include <hip/hip_runtime.h>
#include <hip/hip_fp16.h>

#define TPB 256

// ---------------- CSR build ----------------

__global__ void k_count(const int* __restrict__ dstA, int* __restrict__ cnt, int E) {
    int e = blockIdx.x * blockDim.x + threadIdx.x;
    if (e >= E) return;
    atomicAdd(&cnt[dstA[e]], 1);
}

// ---- 3-phase exclusive scan of (cnt[i]+1) ----
__global__ void k_scan_part(const int* __restrict__ cnt, int* __restrict__ part,
                            int N, int ept) {
    __shared__ int sm[TPB];
    int tid = threadIdx.x;
    int beg = (blockIdx.x * TPB + tid) * ept;
    int s = 0;
    for (int u = 0; u < ept; ++u) {
        int i = beg + u;
        if (i < N) s += cnt[i] + 1;
    }
    sm[tid] = s;
    __syncthreads();
    for (int st = TPB / 2; st; st >>= 1) {
        if (tid < st) sm[tid] += sm[tid + st];
        __syncthreads();
    }
    if (tid == 0) part[blockIdx.x] = sm[0];
}

__global__ void k_scan_top(int* __restrict__ part, int* __restrict__ rowptr,
                           int nb, int N) {
    int lane = threadIdx.x & 63;
    int orig = (lane < nb) ? part[lane] : 0;
    int v = orig;
    #pragma unroll
    for (int ofs = 1; ofs < 64; ofs <<= 1) {
        int t = __shfl_up(v, ofs);
        if (lane >= ofs) v += t;
    }
    if (lane < nb) part[lane] = v - orig;
    if (lane == 63) rowptr[N] = v;
}

__global__ void k_scan_fin(const int* __restrict__ cnt, const int* __restrict__ part,
                           int* __restrict__ rowptr, int N, int ept) {
    __shared__ int wsum[TPB / 64];
    int tid = threadIdx.x;
    int lane = tid & 63, wid = tid >> 6;
    int beg = (blockIdx.x * TPB + tid) * ept;
    int s = 0;
    for (int u = 0; u < ept; ++u) {
        int i = beg + u;
        if (i < N) s += cnt[i] + 1;
    }
    int v = s;
    #pragma unroll
    for (int ofs = 1; ofs < 64; ofs <<= 1) {
        int t = __shfl_up(v, ofs);
        if (lane >= ofs) v += t;
    }
    if (lane == 63) wsum[wid] = v;
    __syncthreads();
    int woff = 0;
    for (int k = 0; k < wid; ++k) woff += wsum[k];
    int acc = (v - s) + woff + part[blockIdx.x];
    for (int u = 0; u < ept; ++u) {
        int i = beg + u;
        if (i < N) { rowptr[i] = acc; acc += cnt[i] + 1; }
    }
}

// cefs[slot] = (f0, f1, f2, bitcast(src))
__global__ void k_fill(const int* __restrict__ srcA, const int* __restrict__ dstA,
                       const float* __restrict__ ef,
                       const int* __restrict__ rowptr, int* __restrict__ fill,
                       float4* __restrict__ cefs, int E) {
    int e = blockIdx.x * blockDim.x + threadIdx.x;
    if (e >= E) return;
    int d = dstA[e];
    int pos = atomicAdd(&fill[d], 1);
    int slot = rowptr[d] + pos;
    cefs[slot] = make_float4(ef[e * 3 + 0], ef[e * 3 + 1], ef[e * 3 + 2],
                             __int_as_float(srcA[e]));
}

__global__ void k_selfloop(const int* __restrict__ rowptr, const int* __restrict__ cnt,
                           float4* __restrict__ cefs, int N) {
    int i = blockIdx.x * blockDim.x + threadIdx.x;
    if (i >= N) return;
    int b = rowptr[i];
    int c = cnt[i];
    float s0 = 0.f, s1 = 0.f, s2 = 0.f;
    for (int s = b; s < b + c; ++s) {
        float4 q = cefs[s];
        s0 += q.x; s1 += q.y; s2 += q.z;
    }
    float inv = 1.0f / (float)max(c, 1);
    cefs[b + c] = make_float4(s0 * inv, s1 * inv, s2 * inv, __int_as_float(i));
}

// ---------------- layer-0 linear (F=5): simple register-tiled ----------------
template <int F, int HC>
__global__ void k_lin_s(const float* __restrict__ xin,
                        const float* __restrict__ wl, const float* __restrict__ bl,
                        const float* __restrict__ wr, const float* __restrict__ br,
                        __half* __restrict__ xl16, float* __restrict__ xr, int N) {
    constexpr int OPT = HC / 16;
    __shared__ float xs[32][F + 1];
    int n0 = blockIdx.x * 32;
    int tid = threadIdx.x;

    for (int idx = tid; idx < 32 * F; idx += TPB) {
        int n = idx / F, k = idx - n * F;
        int gn = n0 + n;
        xs[n][k] = (gn < N) ? xin[(size_t)gn * F + k] : 0.f;
    }
    __syncthreads();

    int og = tid & 31;
    int ng = tid >> 5;
    int o0 = og * OPT;
    bool isL = o0 < HC;
    int col = isL ? o0 : o0 - HC;
    const float* wp = isL ? wl : wr;
    const float* bp = isL ? bl : br;

    float acc[4][OPT];
    #pragma unroll
    for (int j = 0; j < 4; ++j)
        #pragma unroll
        for (int m = 0; m < OPT; ++m) acc[j][m] = 0.f;

    #pragma unroll
    for (int k = 0; k < F; ++k) {
        float wv[OPT];
        #pragma unroll
        for (int m = 0; m < OPT; m += 4)
            *reinterpret_cast<float4*>(&wv[m]) =
                *reinterpret_cast<const float4*>(wp + (size_t)k * HC + col + m);
        #pragma unroll
        for (int j = 0; j < 4; ++j) {
            float xv = xs[ng * 4 + j][k];
            #pragma unroll
            for (int m = 0; m < OPT; ++m) acc[j][m] = fmaf(xv, wv[m], acc[j][m]);
        }
    }

    float bias[OPT];
    #pragma unroll
    for (int m = 0; m < OPT; ++m) bias[m] = bp[col + m];

    #pragma unroll
    for (int j = 0; j < 4; ++j) {
        int node = n0 + ng * 4 + j;
        if (node >= N) continue;
        if (isL) {
            #pragma unroll
            for (int m = 0; m < OPT; m += 2) {
                __half2 hv = __half2(__float2half(acc[j][m] + bias[m]),
                                     __float2half(acc[j][m + 1] + bias[m + 1]));
                *reinterpret_cast<__half2*>(xl16 + (size_t)node * HC + col + m) = hv;
            }
        } else {
            #pragma unroll
            for (int m = 0; m < OPT; m += 4) {
                float4 fv = make_float4(acc[j][m] + bias[m], acc[j][m + 1] + bias[m + 1],
                                        acc[j][m + 2] + bias[m + 2], acc[j][m + 3] + bias[m + 3]);
                *reinterpret_cast<float4*>(xr + (size_t)node * HC + col + m) = fv;
            }
        }
    }
}

// ---------------- big linear layers: LDS-staged weights ----------------
// Block: 32 nodes x 2HC outputs. Thread (og=tid&31, ng=tid>>5):
// 4 nodes x {CPT cols of Wl AND CPT cols of Wr}, CPT = HC/32.
template <int F, int HC>
__global__ void k_lin2(const float* __restrict__ xin,
                       const float* __restrict__ wl, const float* __restrict__ bl,
                       const float* __restrict__ wr, const float* __restrict__ br,
                       __half* __restrict__ xl16, float* __restrict__ xr, int N) {
    constexpr int KC = 32;
    constexpr int W2 = 2 * HC;
    constexpr int CPT = HC / 32;               // cols per thread per side (4 or 2)
    constexpr int WITER = KC * W2 / (TPB * 4); // float4 staging iters (exact)
    __shared__ float xs[32][F + 1];
    __shared__ float ws[KC][W2];
    int n0 = blockIdx.x * 32;
    int tid = threadIdx.x;

    for (int idx = tid; idx < 32 * F; idx += TPB) {
        int n = idx / F, k = idx - n * F;
        int gn = n0 + n;
        xs[n][k] = (gn < N) ? xin[(size_t)gn * F + k] : 0.f;
    }

    int og = tid & 31;
    int ng = tid >> 5;
    int col = og * CPT;

    float acc[4][2 * CPT];
    #pragma unroll
    for (int j = 0; j < 4; ++j)
        #pragma unroll
        for (int m = 0; m < 2 * CPT; ++m) acc[j][m] = 0.f;

    for (int kc = 0; kc < F; kc += KC) {
        __syncthreads();  // xs ready (1st iter) / prev chunk ws reads done
        #pragma unroll
        for (int it = 0; it < WITER; ++it) {
            int w4 = (it * TPB + tid) * 4;
            int k = w4 / W2, c = w4 % W2;
            const float* srcp = (c < HC) ? wl + (size_t)(kc + k) * HC + c
                                         : wr + (size_t)(kc + k) * HC + (c - HC);
            *reinterpret_cast<float4*>(&ws[k][c]) = *reinterpret_cast<const float4*>(srcp);
        }
        __syncthreads();
        #pragma unroll
        for (int kk = 0; kk < KC; ++kk) {
            float wv[2 * CPT];
            #pragma unroll
            for (int m = 0; m < CPT; ++m) {
                wv[m] = ws[kk][col + m];
                wv[CPT + m] = ws[kk][HC + col + m];
            }
            #pragma unroll
            for (int j = 0; j < 4; ++j) {
                float xv = xs[ng * 4 + j][kc + kk];
                #pragma unroll
                for (int m = 0; m < 2 * CPT; ++m) acc[j][m] = fmaf(xv, wv[m], acc[j][m]);
            }
        }
    }

    float bL[CPT], bR[CPT];
    #pragma unroll
    for (int m = 0; m < CPT; ++m) { bL[m] = bl[col + m]; bR[m] = br[col + m]; }

    #pragma unroll
    for (int j = 0; j < 4; ++j) {
        int node = n0 + ng * 4 + j;
        if (node >= N) continue;
        #pragma unroll
        for (int m = 0; m < CPT; m += 2) {
            __half2 hv(__float2half(acc[j][m] + bL[m]),
                       __float2half(acc[j][m + 1] + bL[m + 1]));
            *reinterpret_cast<__half2*>(xl16 + (size_t)node * HC + col + m) = hv;
        }
        #pragma unroll
        for (int m = 0; m < CPT; m += 2) {
            float2 fv = make_float2(acc[j][CPT + m] + bR[m],
                                    acc[j][CPT + m + 1] + bR[m + 1]);
            *reinterpret_cast<float2*>(xr + (size_t)node * HC + col + m) = fv;
        }
    }
}

// ---------------- fused GATv2 attention + aggregation ----------------
// Per dst node, online-softmax over its CSR row; dual 4-edge blocks = 8 gathers in flight.
template <int H, int C>
__global__ void k_fused(const int* __restrict__ rowptr,
                        const float4* __restrict__ cefs,
                        const __half* __restrict__ xl16, const float* __restrict__ xr,
                        const float* __restrict__ we, const float* __restrict__ att,
                        const float* __restrict__ cb, float* __restrict__ hout, int N) {
    constexpr int HC = H * C;
    constexpr int PAIRS = HC / 2;
    constexpr int NPW = 64 / PAIRS;
    int wave = (blockIdx.x * blockDim.x + threadIdx.x) >> 6;
    int lane = threadIdx.x & 63;
    int g = lane / PAIRS;
    int p = lane % PAIRS;
    int node = wave * NPW + g;
    bool act = node < N;

    int o0 = 2 * p, o1 = 2 * p + 1;
    float xr0 = 0.f, xr1 = 0.f;
    int b = 0, len = 0;
    if (act) {
        xr0 = xr[(size_t)node * HC + o0];
        xr1 = xr[(size_t)node * HC + o1];
        b = rowptr[node];
        len = rowptr[node + 1] - b;
    }
    float w0a = we[o0], w0b = we[HC + o0], w0c = we[2 * HC + o0];
    float w1a = we[o1], w1b = we[HC + o1], w1c = we[2 * HC + o1];
    float at0 = att[o0], at1 = att[o1];

    float m_run = -1e30f, den = 0.f, acc0 = 0.f, acc1 = 0.f;

    auto edge4 = [&](int k0, float* L, float* xa, float* xb) {
        #pragma unroll
        for (int u = 0; u < 4; ++u) {
            int kk = k0 + u;
            bool v = kk < len;
            int s = b + (v ? kk : 0);
            float4 q = cefs[s];
            int src = __float_as_int(q.w);
            __half2 hv = *(reinterpret_cast<const __half2*>(xl16 + (size_t)src * HC) + p);
            float2 x2 = __half22float2(hv);
            float s0 = x2.x + xr0 + q.x * w0a + q.y * w0b + q.z * w0c;
            float s1 = x2.y + xr1 + q.x * w1a + q.y * w1b + q.z * w1c;
            s0 = (s0 > 0.f) ? s0 : 0.2f * s0;
            s1 = (s1 > 0.f) ? s1 : 0.2f * s1;
            float partial = at0 * s0 + at1 * s1;
            #pragma unroll
            for (int mk = 1; mk < C / 2; mk <<= 1) partial += __shfl_xor(partial, mk);
            L[u] = v ? partial : -1e30f;
            xa[u] = x2.x;
            xb[u] = x2.y;
        }
    };
    auto merge4 = [&](const float* L, const float* xa, const float* xb) {
        float Lm = fmaxf(fmaxf(L[0], L[1]), fmaxf(L[2], L[3]));
        float nm = fmaxf(m_run, Lm);
        float sc = __expf(m_run - nm);
        float p0 = __expf(L[0] - nm), p1 = __expf(L[1] - nm);
        float p2 = __expf(L[2] - nm), p3 = __expf(L[3] - nm);
        den = den * sc + ((p0 + p1) + (p2 + p3));
        acc0 = fmaf(acc0, sc, fmaf(p0, xa[0], fmaf(p1, xa[1], fmaf(p2, xa[2], p3 * xa[3]))));
        acc1 = fmaf(acc1, sc, fmaf(p0, xb[0], fmaf(p1, xb[1], fmaf(p2, xb[2], p3 * xb[3]))));
        m_run = nm;
    };

    int nk = (len + 7) >> 3;
    for (int kb = 0; kb < nk; ++kb) {
        int k0 = kb * 8;
        float LA[4], xaA[4], xbA[4], LB[4], xaB[4], xbB[4];
        edge4(k0, LA, xaA, xbA);
        edge4(k0 + 4, LB, xaB, xbB);
        merge4(LA, xaA, xbA);
        merge4(LB, xaB, xbB);
    }

    if (act) {
        float inv = 1.0f / den;  // self-loop guarantees den > 0
        float r0 = fmaxf(acc0 * inv + cb[o0], 0.f);
        float r1 = fmaxf(acc1 * inv + cb[o1], 0.f);
        *reinterpret_cast<float2*>(hout + (size_t)node * HC + o0) = make_float2(r0, r1);
    }
}

// ---------------- pooling + final linear ----------------
__global__ void k_pool(const float* __restrict__ h, const int* __restrict__ batch,
                       float* __restrict__ psum, int* __restrict__ pcnt, int N) {
    int o = threadIdx.x & 63;
    int j = threadIdx.x >> 6;
    int nb = blockIdx.x * 32;
    float acc = 0.f;
    int gcur = -1, cntacc = 0;
    for (int jj = j; jj < 32; jj += 4) {
        int node = nb + jj;
        if (node >= N) break;
        int g = batch[node];
        if (g != gcur) {
            if (gcur >= 0) {
                atomicAdd(&psum[gcur * 64 + o], acc);
                if (o == 0) atomicAdd(&pcnt[gcur], cntacc);
            }
            gcur = g; acc = 0.f; cntacc = 0;
        }
        acc += h[(size_t)node * 64 + o];
        ++cntacc;
    }
    if (gcur >= 0) {
        atomicAdd(&psum[gcur * 64 + o], acc);
        if (o == 0) atomicAdd(&pcnt[gcur], cntacc);
    }
}

__global__ void k_final(const float* __restrict__ psum, const int* __restrict__ pcnt,
                        const float* __restrict__ wlin, const float* __restrict__ blin,
                        float* __restrict__ out, int G) {
    int t = blockIdx.x * blockDim.x + threadIdx.x;
    if (t >= G * 32) return;
    int g = t / 32, j = t % 32;
    float acc = 0.f;
    for (int k = 0; k < 64; ++k) acc = fmaf(psum[g * 64 + k], wlin[k * 32 + j], acc);
    float inv = 1.0f / (float)max(pcnt[g], 1);
    out[t] = acc * inv + blin[j];
}

// ---------------- host ----------------

extern "C" void kernel_launch(void* const* d_in, const int* in_sizes, int n_in,
                              void* d_out, int out_size, void* d_ws, size_t ws_size,
                              hipStream_t stream) {
    const float* x = (const float*)d_in[0];
    const int* ei = (const int*)d_in[1];
    const float* ef = (const float*)d_in[2];
    const int* batch = (const int*)d_in[3];

    int N = in_sizes[0] / 5;
    int E = in_sizes[1] / 2;
    int G = out_size / 32;
    int Etot = E + N;
    const int* srcA = ei;
    const int* dstA = ei + E;

    char* w = (char*)d_ws;
    size_t off = 0;
    auto A = [&](size_t bytes) -> void* {
        void* p = w + off;
        off = (off + bytes + 255) & ~(size_t)255;
        return p;
    };
    // zero-init region: cnt0, fill, psum, pcnt
    int* cnt0 = (int*)A((size_t)N * 4);
    int* fill = (int*)A((size_t)N * 4);
    float* psum = (float*)A((size_t)G * 64 * 4);
    int* pcnt = (int*)A((size_t)G * 4);
    size_t zbytes = off;
    int* rowptr = (int*)A((size_t)(N + 1) * 4);
    int* part = (int*)A((size_t)64 * 4);
    float4* cefs = (float4*)A((size_t)Etot * 16);
    __half* xl16 = (__half*)A((size_t)N * 128 * 2);
    float* xr = (float*)A((size_t)N * 128 * 4);
    float* h0 = (float*)A((size_t)N * 128 * 4);
    float* h1 = (float*)A((size_t)N * 128 * 4);

    hipMemsetAsync(d_ws, 0, zbytes, stream);

    dim3 B(TPB);
    k_count<<<(E + TPB - 1) / TPB, B, 0, stream>>>(dstA, cnt0, E);

    int ept = (N + 64 * TPB - 1) / (64 * TPB);
    if (ept < 4) ept = 4;
    int nb = (N + ept * TPB - 1) / (ept * TPB);
    k_scan_part<<<nb, B, 0, stream>>>(cnt0, part, N, ept);
    k_scan_top<<<1, 64, 0, stream>>>(part, rowptr, nb, N);
    k_scan_fin<<<nb, B, 0, stream>>>(cnt0, part, rowptr, N, ept);

    k_fill<<<(E + TPB - 1) / TPB, B, 0, stream>>>(srcA, dstA, ef, rowptr, fill, cefs, E);
    k_selfloop<<<(N + TPB - 1) / TPB, B, 0, stream>>>(rowptr, cnt0, cefs, N);

    float* houts[4] = {h0, h1, h0, h1};

    int nblk = (N + 31) / 32;
    const float* hin = x;
    for (int l = 0; l < 4; ++l) {
        const float* wl  = (const float*)d_in[4 + l * 7 + 0];
        const float* bl  = (const float*)d_in[4 + l * 7 + 1];
        const float* wr  = (const float*)d_in[4 + l * 7 + 2];
        const float* br  = (const float*)d_in[4 + l * 7 + 3];
        const float* we  = (const float*)d_in[4 + l * 7 + 4];
        const float* att = (const float*)d_in[4 + l * 7 + 5];
        const float* cb  = (const float*)d_in[4 + l * 7 + 6];
        int H = (l == 3) ? 2 : 4;
        int C = (l == 0) ? 16 : 32;
        int HC = H * C;

        if (l == 0)      k_lin_s<5, 64>   <<<nblk, B, 0, stream>>>(hin, wl, bl, wr, br, xl16, xr, N);
        else if (l == 1) k_lin2<64, 128>  <<<nblk, B, 0, stream>>>(hin, wl, bl, wr, br, xl16, xr, N);
        else if (l == 2) k_lin2<128, 128> <<<nblk, B, 0, stream>>>(hin, wl, bl, wr, br, xl16, xr, N);
        else             k_lin2<128, 64>  <<<nblk, B, 0, stream>>>(hin, wl, bl, wr, br, xl16, xr, N);

        int npw = 64 / (HC / 2);
        int waves = (N + npw - 1) / npw;
        int blocks = (waves + 3) / 4;
        if (H == 4 && C == 16)
            k_fused<4, 16><<<blocks, B, 0, stream>>>(rowptr, cefs, xl16, xr,
                                                     we, att, cb, houts[l], N);
        else if (H == 4 && C == 32)
            k_fused<4, 32><<<blocks, B, 0, stream>>>(rowptr, cefs, xl16, xr,
                                                     we, att, cb, houts[l], N);
        else
            k_fused<2, 32><<<blocks, B, 0, stream>>>(rowptr, cefs, xl16, xr,
                                                     we, att, cb, houts[l], N);
        hin = houts[l];
    }

    k_pool<<<(N + 31) / 32, B, 0, stream>>>(hin, batch, psum, pcnt, N);
    k_final<<<(G * 32 + TPB - 1) / TPB, B, 0, stream>>>(psum, pcnt,
                                                        (const float*)d_in[32],
                                                        (const float*)d_in[33],
                                                        (float*)d_out, G);
}

// Round 9
// 577.563 us; speedup vs baseline: 1.0504x; 1.0504x over previous
//
#include <hip/hip_runtime.h>
#include <hip/hip_fp16.h>

#define TPB 256

// ---------------- CSR build ----------------

__global__ void k_count(const int* __restrict__ dstA, int* __restrict__ cnt, int E) {
    int e = blockIdx.x * blockDim.x + threadIdx.x;
    if (e >= E) return;
    atomicAdd(&cnt[dstA[e]], 1);
}

// ---- 3-phase exclusive scan of (cnt[i]+1) ----
__global__ void k_scan_part(const int* __restrict__ cnt, int* __restrict__ part,
                            int N, int ept) {
    __shared__ int sm[TPB];
    int tid = threadIdx.x;
    int beg = (blockIdx.x * TPB + tid) * ept;
    int s = 0;
    for (int u = 0; u < ept; ++u) {
        int i = beg + u;
        if (i < N) s += cnt[i] + 1;
    }
    sm[tid] = s;
    __syncthreads();
    for (int st = TPB / 2; st; st >>= 1) {
        if (tid < st) sm[tid] += sm[tid + st];
        __syncthreads();
    }
    if (tid == 0) part[blockIdx.x] = sm[0];
}

__global__ void k_scan_top(int* __restrict__ part, int* __restrict__ rowptr,
                           int nb, int N) {
    int lane = threadIdx.x & 63;
    int orig = (lane < nb) ? part[lane] : 0;
    int v = orig;
    #pragma unroll
    for (int ofs = 1; ofs < 64; ofs <<= 1) {
        int t = __shfl_up(v, ofs);
        if (lane >= ofs) v += t;
    }
    if (lane < nb) part[lane] = v - orig;
    if (lane == 63) rowptr[N] = v;
}

__global__ void k_scan_fin(const int* __restrict__ cnt, const int* __restrict__ part,
                           int* __restrict__ rowptr, int N, int ept) {
    __shared__ int wsum[TPB / 64];
    int tid = threadIdx.x;
    int lane = tid & 63, wid = tid >> 6;
    int beg = (blockIdx.x * TPB + tid) * ept;
    int s = 0;
    for (int u = 0; u < ept; ++u) {
        int i = beg + u;
        if (i < N) s += cnt[i] + 1;
    }
    int v = s;
    #pragma unroll
    for (int ofs = 1; ofs < 64; ofs <<= 1) {
        int t = __shfl_up(v, ofs);
        if (lane >= ofs) v += t;
    }
    if (lane == 63) wsum[wid] = v;
    __syncthreads();
    int woff = 0;
    for (int k = 0; k < wid; ++k) woff += wsum[k];
    int acc = (v - s) + woff + part[blockIdx.x];
    for (int u = 0; u < ept; ++u) {
        int i = beg + u;
        if (i < N) { rowptr[i] = acc; acc += cnt[i] + 1; }
    }
}

// cefs[slot] = (f0, f1, f2, bitcast(src))
__global__ void k_fill(const int* __restrict__ srcA, const int* __restrict__ dstA,
                       const float* __restrict__ ef,
                       const int* __restrict__ rowptr, int* __restrict__ fill,
                       float4* __restrict__ cefs, int E) {
    int e = blockIdx.x * blockDim.x + threadIdx.x;
    if (e >= E) return;
    int d = dstA[e];
    int pos = atomicAdd(&fill[d], 1);
    int slot = rowptr[d] + pos;
    cefs[slot] = make_float4(ef[e * 3 + 0], ef[e * 3 + 1], ef[e * 3 + 2],
                             __int_as_float(srcA[e]));
}

__global__ void k_selfloop(const int* __restrict__ rowptr, const int* __restrict__ cnt,
                           float4* __restrict__ cefs, int N) {
    int i = blockIdx.x * blockDim.x + threadIdx.x;
    if (i >= N) return;
    int b = rowptr[i];
    int c = cnt[i];
    float s0 = 0.f, s1 = 0.f, s2 = 0.f;
    for (int s = b; s < b + c; ++s) {
        float4 q = cefs[s];
        s0 += q.x; s1 += q.y; s2 += q.z;
    }
    float inv = 1.0f / (float)max(c, 1);
    cefs[b + c] = make_float4(s0 * inv, s1 * inv, s2 * inv, __int_as_float(i));
}

// ---------------- layer-0 linear (F=5): simple register-tiled ----------------
template <int F, int HC>
__global__ void k_lin_s(const float* __restrict__ xin,
                        const float* __restrict__ wl, const float* __restrict__ bl,
                        const float* __restrict__ wr, const float* __restrict__ br,
                        __half* __restrict__ xl16, float* __restrict__ xr, int N) {
    constexpr int OPT = HC / 16;
    __shared__ float xs[32][F + 1];
    int n0 = blockIdx.x * 32;
    int tid = threadIdx.x;

    for (int idx = tid; idx < 32 * F; idx += TPB) {
        int n = idx / F, k = idx - n * F;
        int gn = n0 + n;
        xs[n][k] = (gn < N) ? xin[(size_t)gn * F + k] : 0.f;
    }
    __syncthreads();

    int og = tid & 31;
    int ng = tid >> 5;
    int o0 = og * OPT;
    bool isL = o0 < HC;
    int col = isL ? o0 : o0 - HC;
    const float* wp = isL ? wl : wr;
    const float* bp = isL ? bl : br;

    float acc[4][OPT];
    #pragma unroll
    for (int j = 0; j < 4; ++j)
        #pragma unroll
        for (int m = 0; m < OPT; ++m) acc[j][m] = 0.f;

    #pragma unroll
    for (int k = 0; k < F; ++k) {
        float wv[OPT];
        #pragma unroll
        for (int m = 0; m < OPT; m += 4)
            *reinterpret_cast<float4*>(&wv[m]) =
                *reinterpret_cast<const float4*>(wp + (size_t)k * HC + col + m);
        #pragma unroll
        for (int j = 0; j < 4; ++j) {
            float xv = xs[ng * 4 + j][k];
            #pragma unroll
            for (int m = 0; m < OPT; ++m) acc[j][m] = fmaf(xv, wv[m], acc[j][m]);
        }
    }

    float bias[OPT];
    #pragma unroll
    for (int m = 0; m < OPT; ++m) bias[m] = bp[col + m];

    #pragma unroll
    for (int j = 0; j < 4; ++j) {
        int node = n0 + ng * 4 + j;
        if (node >= N) continue;
        if (isL) {
            #pragma unroll
            for (int m = 0; m < OPT; m += 2) {
                __half2 hv = __half2(__float2half(acc[j][m] + bias[m]),
                                     __float2half(acc[j][m + 1] + bias[m + 1]));
                *reinterpret_cast<__half2*>(xl16 + (size_t)node * HC + col + m) = hv;
            }
        } else {
            #pragma unroll
            for (int m = 0; m < OPT; m += 4) {
                float4 fv = make_float4(acc[j][m] + bias[m], acc[j][m + 1] + bias[m + 1],
                                        acc[j][m + 2] + bias[m + 2], acc[j][m + 3] + bias[m + 3]);
                *reinterpret_cast<float4*>(xr + (size_t)node * HC + col + m) = fv;
            }
        }
    }
}

// ---------------- big linear layers: LDS-staged weights ----------------
template <int F, int HC>
__global__ void k_lin2(const float* __restrict__ xin,
                       const float* __restrict__ wl, const float* __restrict__ bl,
                       const float* __restrict__ wr, const float* __restrict__ br,
                       __half* __restrict__ xl16, float* __restrict__ xr, int N) {
    constexpr int KC = 32;
    constexpr int W2 = 2 * HC;
    constexpr int CPT = HC / 32;               // cols per thread per side (4 or 2)
    constexpr int WITER = KC * W2 / (TPB * 4); // float4 staging iters (exact)
    __shared__ float xs[32][F + 1];
    __shared__ float ws[KC][W2];
    int n0 = blockIdx.x * 32;
    int tid = threadIdx.x;

    for (int idx = tid; idx < 32 * F; idx += TPB) {
        int n = idx / F, k = idx - n * F;
        int gn = n0 + n;
        xs[n][k] = (gn < N) ? xin[(size_t)gn * F + k] : 0.f;
    }

    int og = tid & 31;
    int ng = tid >> 5;
    int col = og * CPT;

    float acc[4][2 * CPT];
    #pragma unroll
    for (int j = 0; j < 4; ++j)
        #pragma unroll
        for (int m = 0; m < 2 * CPT; ++m) acc[j][m] = 0.f;

    for (int kc = 0; kc < F; kc += KC) {
        __syncthreads();
        #pragma unroll
        for (int it = 0; it < WITER; ++it) {
            int w4 = (it * TPB + tid) * 4;
            int k = w4 / W2, c = w4 % W2;
            const float* srcp = (c < HC) ? wl + (size_t)(kc + k) * HC + c
                                         : wr + (size_t)(kc + k) * HC + (c - HC);
            *reinterpret_cast<float4*>(&ws[k][c]) = *reinterpret_cast<const float4*>(srcp);
        }
        __syncthreads();
        #pragma unroll
        for (int kk = 0; kk < KC; ++kk) {
            float wv[2 * CPT];
            #pragma unroll
            for (int m = 0; m < CPT; ++m) {
                wv[m] = ws[kk][col + m];
                wv[CPT + m] = ws[kk][HC + col + m];
            }
            #pragma unroll
            for (int j = 0; j < 4; ++j) {
                float xv = xs[ng * 4 + j][kc + kk];
                #pragma unroll
                for (int m = 0; m < 2 * CPT; ++m) acc[j][m] = fmaf(xv, wv[m], acc[j][m]);
            }
        }
    }

    float bL[CPT], bR[CPT];
    #pragma unroll
    for (int m = 0; m < CPT; ++m) { bL[m] = bl[col + m]; bR[m] = br[col + m]; }

    #pragma unroll
    for (int j = 0; j < 4; ++j) {
        int node = n0 + ng * 4 + j;
        if (node >= N) continue;
        #pragma unroll
        for (int m = 0; m < CPT; m += 2) {
            __half2 hv(__float2half(acc[j][m] + bL[m]),
                       __float2half(acc[j][m + 1] + bL[m + 1]));
            *reinterpret_cast<__half2*>(xl16 + (size_t)node * HC + col + m) = hv;
        }
        #pragma unroll
        for (int m = 0; m < CPT; m += 2) {
            float2 fv = make_float2(acc[j][CPT + m] + bR[m],
                                    acc[j][CPT + m + 1] + bR[m + 1]);
            *reinterpret_cast<float2*>(xr + (size_t)node * HC + col + m) = fv;
        }
    }
}

// ---------------- fused GATv2 attention + aggregation ----------------
// Per dst node, online-softmax over its CSR row; single 4-edge block (proven R6 shape).
// log2-domain softmax (att pre-scaled by log2e, raw v_exp_f32) + sign-select lrelu.
template <int H, int C>
__global__ void k_fused(const int* __restrict__ rowptr,
                        const float4* __restrict__ cefs,
                        const __half* __restrict__ xl16, const float* __restrict__ xr,
                        const float* __restrict__ we, const float* __restrict__ att,
                        const float* __restrict__ cb, float* __restrict__ hout, int N) {
    constexpr int HC = H * C;
    constexpr int PAIRS = HC / 2;
    constexpr int NPW = 64 / PAIRS;
    int wave = (blockIdx.x * blockDim.x + threadIdx.x) >> 6;
    int lane = threadIdx.x & 63;
    int g = lane / PAIRS;
    int p = lane % PAIRS;
    int node = wave * NPW + g;
    bool act = node < N;

    int o0 = 2 * p, o1 = 2 * p + 1;
    float xr0 = 0.f, xr1 = 0.f;
    int b = 0, len = 0;
    if (act) {
        xr0 = xr[(size_t)node * HC + o0];
        xr1 = xr[(size_t)node * HC + o1];
        b = rowptr[node];
        len = rowptr[node + 1] - b;
    }
    float w0a = we[o0], w0b = we[HC + o0], w0c = we[2 * HC + o0];
    float w1a = we[o1], w1b = we[HC + o1], w1c = we[2 * HC + o1];
    // att scaled by log2(e): logits live in the log2 domain, exp -> raw v_exp_f32
    const float LOG2E = 1.44269504088896340736f;
    float at0 = att[o0] * LOG2E, at1 = att[o1] * LOG2E;
    float at0s = at0 * 0.2f, at1s = at1 * 0.2f;

    float m_run = -1e30f, den = 0.f, acc0 = 0.f, acc1 = 0.f;

    int nk = (len + 3) >> 2;
    for (int kb = 0; kb < nk; ++kb) {
        int k0 = kb * 4;
        float L[4], xa[4], xb[4];
        #pragma unroll
        for (int u = 0; u < 4; ++u) {
            int kk = k0 + u;
            bool v = kk < len;
            int s = b + (v ? kk : 0);
            float4 q = cefs[s];
            int src = __float_as_int(q.w);
            __half2 hv = *(reinterpret_cast<const __half2*>(xl16 + (size_t)src * HC) + p);
            float2 x2 = __half22float2(hv);
            float s0 = x2.x + xr0 + q.x * w0a + q.y * w0b + q.z * w0c;
            float s1 = x2.y + xr1 + q.x * w1a + q.y * w1b + q.z * w1c;
            float m0 = (s0 > 0.f) ? at0 : at0s;   // at*lrelu(s) == (s>0?at:0.2at)*s
            float m1 = (s1 > 0.f) ? at1 : at1s;
            float partial = fmaf(m1, s1, m0 * s0);
            #pragma unroll
            for (int mk = 1; mk < C / 2; mk <<= 1) partial += __shfl_xor(partial, mk);
            L[u] = v ? partial : -1e30f;
            xa[u] = x2.x;
            xb[u] = x2.y;
        }
        float Lm = fmaxf(fmaxf(L[0], L[1]), fmaxf(L[2], L[3]));
        float nm = fmaxf(m_run, Lm);
        float sc = __builtin_amdgcn_exp2f(m_run - nm);
        float p0 = __builtin_amdgcn_exp2f(L[0] - nm);
        float p1 = __builtin_amdgcn_exp2f(L[1] - nm);
        float p2 = __builtin_amdgcn_exp2f(L[2] - nm);
        float p3 = __builtin_amdgcn_exp2f(L[3] - nm);
        den = den * sc + ((p0 + p1) + (p2 + p3));
        acc0 = fmaf(acc0, sc, fmaf(p0, xa[0], fmaf(p1, xa[1], fmaf(p2, xa[2], p3 * xa[3]))));
        acc1 = fmaf(acc1, sc, fmaf(p0, xb[0], fmaf(p1, xb[1], fmaf(p2, xb[2], p3 * xb[3]))));
        m_run = nm;
    }

    if (act) {
        float inv = 1.0f / den;  // self-loop guarantees den > 0
        float r0 = fmaxf(acc0 * inv + cb[o0], 0.f);
        float r1 = fmaxf(acc1 * inv + cb[o1], 0.f);
        *reinterpret_cast<float2*>(hout + (size_t)node * HC + o0) = make_float2(r0, r1);
    }
}

// ---------------- pooling + final linear ----------------
__global__ void k_pool(const float* __restrict__ h, const int* __restrict__ batch,
                       float* __restrict__ psum, int* __restrict__ pcnt, int N) {
    int o = threadIdx.x & 63;
    int j = threadIdx.x >> 6;
    int nb = blockIdx.x * 32;
    float acc = 0.f;
    int gcur = -1, cntacc = 0;
    for (int jj = j; jj < 32; jj += 4) {
        int node = nb + jj;
        if (node >= N) break;
        int g = batch[node];
        if (g != gcur) {
            if (gcur >= 0) {
                atomicAdd(&psum[gcur * 64 + o], acc);
                if (o == 0) atomicAdd(&pcnt[gcur], cntacc);
            }
            gcur = g; acc = 0.f; cntacc = 0;
        }
        acc += h[(size_t)node * 64 + o];
        ++cntacc;
    }
    if (gcur >= 0) {
        atomicAdd(&psum[gcur * 64 + o], acc);
        if (o == 0) atomicAdd(&pcnt[gcur], cntacc);
    }
}

__global__ void k_final(const float* __restrict__ psum, const int* __restrict__ pcnt,
                        const float* __restrict__ wlin, const float* __restrict__ blin,
                        float* __restrict__ out, int G) {
    int t = blockIdx.x * blockDim.x + threadIdx.x;
    if (t >= G * 32) return;
    int g = t / 32, j = t % 32;
    float acc = 0.f;
    for (int k = 0; k < 64; ++k) acc = fmaf(psum[g * 64 + k], wlin[k * 32 + j], acc);
    float inv = 1.0f / (float)max(pcnt[g], 1);
    out[t] = acc * inv + blin[j];
}

// ---------------- host ----------------

extern "C" void kernel_launch(void* const* d_in, const int* in_sizes, int n_in,
                              void* d_out, int out_size, void* d_ws, size_t ws_size,
                              hipStream_t stream) {
    const float* x = (const float*)d_in[0];
    const int* ei = (const int*)d_in[1];
    const float* ef = (const float*)d_in[2];
    const int* batch = (const int*)d_in[3];

    int N = in_sizes[0] / 5;
    int E = in_sizes[1] / 2;
    int G = out_size / 32;
    int Etot = E + N;
    const int* srcA = ei;
    const int* dstA = ei + E;

    char* w = (char*)d_ws;
    size_t off = 0;
    auto A = [&](size_t bytes) -> void* {
        void* p = w + off;
        off = (off + bytes + 255) & ~(size_t)255;
        return p;
    };
    // zero-init region: cnt0, fill, psum, pcnt
    int* cnt0 = (int*)A((size_t)N * 4);
    int* fill = (int*)A((size_t)N * 4);
    float* psum = (float*)A((size_t)G * 64 * 4);
    int* pcnt = (int*)A((size_t)G * 4);
    size_t zbytes = off;
    int* rowptr = (int*)A((size_t)(N + 1) * 4);
    int* part = (int*)A((size_t)64 * 4);
    float4* cefs = (float4*)A((size_t)Etot * 16);
    __half* xl16 = (__half*)A((size_t)N * 128 * 2);
    float* xr = (float*)A((size_t)N * 128 * 4);
    float* h0 = (float*)A((size_t)N * 128 * 4);
    float* h1 = (float*)A((size_t)N * 128 * 4);

    hipMemsetAsync(d_ws, 0, zbytes, stream);

    dim3 B(TPB);
    k_count<<<(E + TPB - 1) / TPB, B, 0, stream>>>(dstA, cnt0, E);

    int ept = (N + 64 * TPB - 1) / (64 * TPB);
    if (ept < 4) ept = 4;
    int nb = (N + ept * TPB - 1) / (ept * TPB);
    k_scan_part<<<nb, B, 0, stream>>>(cnt0, part, N, ept);
    k_scan_top<<<1, 64, 0, stream>>>(part, rowptr, nb, N);
    k_scan_fin<<<nb, B, 0, stream>>>(cnt0, part, rowptr, N, ept);

    k_fill<<<(E + TPB - 1) / TPB, B, 0, stream>>>(srcA, dstA, ef, rowptr, fill, cefs, E);
    k_selfloop<<<(N + TPB - 1) / TPB, B, 0, stream>>>(rowptr, cnt0, cefs, N);

    float* houts[4] = {h0, h1, h0, h1};

    int nblk = (N + 31) / 32;
    const float* hin = x;
    for (int l = 0; l < 4; ++l) {
        const float* wl  = (const float*)d_in[4 + l * 7 + 0];
        const float* bl  = (const float*)d_in[4 + l * 7 + 1];
        const float* wr  = (const float*)d_in[4 + l * 7 + 2];
        const float* br  = (const float*)d_in[4 + l * 7 + 3];
        const float* we  = (const float*)d_in[4 + l * 7 + 4];
        const float* att = (const float*)d_in[4 + l * 7 + 5];
        const float* cb  = (const float*)d_in[4 + l * 7 + 6];
        int H = (l == 3) ? 2 : 4;
        int C = (l == 0) ? 16 : 32;
        int HC = H * C;

        if (l == 0)      k_lin_s<5, 64>   <<<nblk, B, 0, stream>>>(hin, wl, bl, wr, br, xl16, xr, N);
        else if (l == 1) k_lin2<64, 128>  <<<nblk, B, 0, stream>>>(hin, wl, bl, wr, br, xl16, xr, N);
        else if (l == 2) k_lin2<128, 128> <<<nblk, B, 0, stream>>>(hin, wl, bl, wr, br, xl16, xr, N);
        else             k_lin2<128, 64>  <<<nblk, B, 0, stream>>>(hin, wl, bl, wr, br, xl16, xr, N);

        int npw = 64 / (HC / 2);
        int waves = (N + npw - 1) / npw;
        int blocks = (waves + 3) / 4;
        if (H == 4 && C == 16)
            k_fused<4, 16><<<blocks, B, 0, stream>>>(rowptr, cefs, xl16, xr,
                                                     we, att, cb, houts[l], N);
        else if (H == 4 && C == 32)
            k_fused<4, 32><<<blocks, B, 0, stream>>>(rowptr, cefs, xl16, xr,
                                                     we, att, cb, houts[l], N);
        else
            k_fused<2, 32><<<blocks, B, 0, stream>>>(rowptr, cefs, xl16, xr,
                                                     we, att, cb, houts[l], N);
        hin = houts[l];
    }

    k_pool<<<(N + 31) / 32, B, 0, stream>>>(hin, batch, psum, pcnt, N);
    k_final<<<(G * 32 + TPB - 1) / TPB, B, 0, stream>>>(psum, pcnt,
                                                        (const float*)d_in[32],
                                                        (const float*)d_in[33],
                                                        (float*)d_out, G);
}

// Round 11
// 542.164 us; speedup vs baseline: 1.1189x; 1.0653x over previous
//
#include <hip/hip_runtime.h>
#include <hip/hip_fp16.h>

#define TPB 256

typedef _Float16 hv2 __attribute__((ext_vector_type(2)));

// cvt_pkrtz returns an __fp16 vector; bit-cast to our _Float16 vector type
static __device__ __forceinline__ hv2 pkrtz(float a, float b) {
    auto t = __builtin_amdgcn_cvt_pkrtz(a, b);
    return __builtin_bit_cast(hv2, t);
}

// ---------------- CSR build ----------------

__global__ void k_count(const int* __restrict__ dstA, int* __restrict__ cnt, int E) {
    int e = blockIdx.x * blockDim.x + threadIdx.x;
    if (e >= E) return;
    atomicAdd(&cnt[dstA[e]], 1);
}

// ---- 3-phase exclusive scan of (cnt[i]+1) ----
__global__ void k_scan_part(const int* __restrict__ cnt, int* __restrict__ part,
                            int N, int ept) {
    __shared__ int sm[TPB];
    int tid = threadIdx.x;
    int beg = (blockIdx.x * TPB + tid) * ept;
    int s = 0;
    for (int u = 0; u < ept; ++u) {
        int i = beg + u;
        if (i < N) s += cnt[i] + 1;
    }
    sm[tid] = s;
    __syncthreads();
    for (int st = TPB / 2; st; st >>= 1) {
        if (tid < st) sm[tid] += sm[tid + st];
        __syncthreads();
    }
    if (tid == 0) part[blockIdx.x] = sm[0];
}

__global__ void k_scan_top(int* __restrict__ part, int* __restrict__ rowptr,
                           int nb, int N) {
    int lane = threadIdx.x & 63;
    int orig = (lane < nb) ? part[lane] : 0;
    int v = orig;
    #pragma unroll
    for (int ofs = 1; ofs < 64; ofs <<= 1) {
        int t = __shfl_up(v, ofs);
        if (lane >= ofs) v += t;
    }
    if (lane < nb) part[lane] = v - orig;
    if (lane == 63) rowptr[N] = v;
}

__global__ void k_scan_fin(const int* __restrict__ cnt, const int* __restrict__ part,
                           int* __restrict__ rowptr, int N, int ept) {
    __shared__ int wsum[TPB / 64];
    int tid = threadIdx.x;
    int lane = tid & 63, wid = tid >> 6;
    int beg = (blockIdx.x * TPB + tid) * ept;
    int s = 0;
    for (int u = 0; u < ept; ++u) {
        int i = beg + u;
        if (i < N) s += cnt[i] + 1;
    }
    int v = s;
    #pragma unroll
    for (int ofs = 1; ofs < 64; ofs <<= 1) {
        int t = __shfl_up(v, ofs);
        if (lane >= ofs) v += t;
    }
    if (lane == 63) wsum[wid] = v;
    __syncthreads();
    int woff = 0;
    for (int k = 0; k < wid; ++k) woff += wsum[k];
    int acc = (v - s) + woff + part[blockIdx.x];
    for (int u = 0; u < ept; ++u) {
        int i = beg + u;
        if (i < N) { rowptr[i] = acc; acc += cnt[i] + 1; }
    }
}

// cefs[slot] = (f0, f1, f2, bitcast(src))
__global__ void k_fill(const int* __restrict__ srcA, const int* __restrict__ dstA,
                       const float* __restrict__ ef,
                       const int* __restrict__ rowptr, int* __restrict__ fill,
                       float4* __restrict__ cefs, int E) {
    int e = blockIdx.x * blockDim.x + threadIdx.x;
    if (e >= E) return;
    int d = dstA[e];
    int pos = atomicAdd(&fill[d], 1);
    int slot = rowptr[d] + pos;
    cefs[slot] = make_float4(ef[e * 3 + 0], ef[e * 3 + 1], ef[e * 3 + 2],
                             __int_as_float(srcA[e]));
}

__global__ void k_selfloop(const int* __restrict__ rowptr, const int* __restrict__ cnt,
                           float4* __restrict__ cefs, int N) {
    int i = blockIdx.x * blockDim.x + threadIdx.x;
    if (i >= N) return;
    int b = rowptr[i];
    int c = cnt[i];
    float s0 = 0.f, s1 = 0.f, s2 = 0.f;
    for (int s = b; s < b + c; ++s) {
        float4 q = cefs[s];
        s0 += q.x; s1 += q.y; s2 += q.z;
    }
    float inv = 1.0f / (float)max(c, 1);
    cefs[b + c] = make_float4(s0 * inv, s1 * inv, s2 * inv, __int_as_float(i));
}

// ---------------- layer-0 linear (F=5): simple register-tiled ----------------
template <int F, int HC>
__global__ void k_lin_s(const float* __restrict__ xin,
                        const float* __restrict__ wl, const float* __restrict__ bl,
                        const float* __restrict__ wr, const float* __restrict__ br,
                        __half* __restrict__ xl16, __half* __restrict__ xr16, int N) {
    constexpr int OPT = HC / 16;
    __shared__ float xs[32][F + 1];
    int n0 = blockIdx.x * 32;
    int tid = threadIdx.x;

    for (int idx = tid; idx < 32 * F; idx += TPB) {
        int n = idx / F, k = idx - n * F;
        int gn = n0 + n;
        xs[n][k] = (gn < N) ? xin[(size_t)gn * F + k] : 0.f;
    }
    __syncthreads();

    int og = tid & 31;
    int ng = tid >> 5;
    int o0 = og * OPT;
    bool isL = o0 < HC;
    int col = isL ? o0 : o0 - HC;
    const float* wp = isL ? wl : wr;
    const float* bp = isL ? bl : br;
    __half* outp = isL ? xl16 : xr16;

    float acc[4][OPT];
    #pragma unroll
    for (int j = 0; j < 4; ++j)
        #pragma unroll
        for (int m = 0; m < OPT; ++m) acc[j][m] = 0.f;

    #pragma unroll
    for (int k = 0; k < F; ++k) {
        float wv[OPT];
        #pragma unroll
        for (int m = 0; m < OPT; m += 4)
            *reinterpret_cast<float4*>(&wv[m]) =
                *reinterpret_cast<const float4*>(wp + (size_t)k * HC + col + m);
        #pragma unroll
        for (int j = 0; j < 4; ++j) {
            float xv = xs[ng * 4 + j][k];
            #pragma unroll
            for (int m = 0; m < OPT; ++m) acc[j][m] = fmaf(xv, wv[m], acc[j][m]);
        }
    }

    float bias[OPT];
    #pragma unroll
    for (int m = 0; m < OPT; ++m) bias[m] = bp[col + m];

    #pragma unroll
    for (int j = 0; j < 4; ++j) {
        int node = n0 + ng * 4 + j;
        if (node >= N) continue;
        #pragma unroll
        for (int m = 0; m < OPT; m += 2) {
            __half2 hv = __half2(__float2half(acc[j][m] + bias[m]),
                                 __float2half(acc[j][m + 1] + bias[m + 1]));
            *reinterpret_cast<__half2*>(outp + (size_t)node * HC + col + m) = hv;
        }
    }
}

// ---------------- big linear layers: LDS-staged weights ----------------
template <int F, int HC>
__global__ void k_lin2(const float* __restrict__ xin,
                       const float* __restrict__ wl, const float* __restrict__ bl,
                       const float* __restrict__ wr, const float* __restrict__ br,
                       __half* __restrict__ xl16, __half* __restrict__ xr16, int N) {
    constexpr int KC = 32;
    constexpr int W2 = 2 * HC;
    constexpr int CPT = HC / 32;               // cols per thread per side (4 or 2)
    constexpr int WITER = KC * W2 / (TPB * 4); // float4 staging iters (exact)
    __shared__ float xs[32][F + 1];
    __shared__ float ws[KC][W2];
    int n0 = blockIdx.x * 32;
    int tid = threadIdx.x;

    for (int idx = tid; idx < 32 * F; idx += TPB) {
        int n = idx / F, k = idx - n * F;
        int gn = n0 + n;
        xs[n][k] = (gn < N) ? xin[(size_t)gn * F + k] : 0.f;
    }

    int og = tid & 31;
    int ng = tid >> 5;
    int col = og * CPT;

    float acc[4][2 * CPT];
    #pragma unroll
    for (int j = 0; j < 4; ++j)
        #pragma unroll
        for (int m = 0; m < 2 * CPT; ++m) acc[j][m] = 0.f;

    for (int kc = 0; kc < F; kc += KC) {
        __syncthreads();
        #pragma unroll
        for (int it = 0; it < WITER; ++it) {
            int w4 = (it * TPB + tid) * 4;
            int k = w4 / W2, c = w4 % W2;
            const float* srcp = (c < HC) ? wl + (size_t)(kc + k) * HC + c
                                         : wr + (size_t)(kc + k) * HC + (c - HC);
            *reinterpret_cast<float4*>(&ws[k][c]) = *reinterpret_cast<const float4*>(srcp);
        }
        __syncthreads();
        #pragma unroll
        for (int kk = 0; kk < KC; ++kk) {
            float wv[2 * CPT];
            #pragma unroll
            for (int m = 0; m < CPT; ++m) {
                wv[m] = ws[kk][col + m];
                wv[CPT + m] = ws[kk][HC + col + m];
            }
            #pragma unroll
            for (int j = 0; j < 4; ++j) {
                float xv = xs[ng * 4 + j][kc + kk];
                #pragma unroll
                for (int m = 0; m < 2 * CPT; ++m) acc[j][m] = fmaf(xv, wv[m], acc[j][m]);
            }
        }
    }

    float bL[CPT], bR[CPT];
    #pragma unroll
    for (int m = 0; m < CPT; ++m) { bL[m] = bl[col + m]; bR[m] = br[col + m]; }

    #pragma unroll
    for (int j = 0; j < 4; ++j) {
        int node = n0 + ng * 4 + j;
        if (node >= N) continue;
        #pragma unroll
        for (int m = 0; m < CPT; m += 2) {
            __half2 hv(__float2half(acc[j][m] + bL[m]),
                       __float2half(acc[j][m + 1] + bL[m + 1]));
            *reinterpret_cast<__half2*>(xl16 + (size_t)node * HC + col + m) = hv;
        }
        #pragma unroll
        for (int m = 0; m < CPT; m += 2) {
            __half2 hv(__float2half(acc[j][CPT + m] + bR[m]),
                       __float2half(acc[j][CPT + m + 1] + bR[m + 1]));
            *reinterpret_cast<__half2*>(xr16 + (size_t)node * HC + col + m) = hv;
        }
    }
}

// ---------------- fused GATv2 attention + aggregation ----------------
// Packed-f16 edge math: pk_add / pk_max / dot2, f32 edge-term + softmax state.
template <int H, int C>
__global__ void k_fused(const int* __restrict__ rowptr,
                        const float4* __restrict__ cefs,
                        const __half* __restrict__ xl16, const __half* __restrict__ xr16,
                        const float* __restrict__ we, const float* __restrict__ att,
                        const float* __restrict__ cb, float* __restrict__ hout, int N) {
    constexpr int HC = H * C;
    constexpr int PAIRS = HC / 2;
    constexpr int NPW = 64 / PAIRS;
    const _Float16* xl = reinterpret_cast<const _Float16*>(xl16);
    int wave = (blockIdx.x * blockDim.x + threadIdx.x) >> 6;
    int lane = threadIdx.x & 63;
    int g = lane / PAIRS;
    int p = lane % PAIRS;
    int node = wave * NPW + g;
    bool act = node < N;

    int o0 = 2 * p, o1 = 2 * p + 1;
    float xr0 = 0.f, xr1 = 0.f;
    int b = 0, len = 0;
    if (act) {
        hv2 xr01 = *reinterpret_cast<const hv2*>(
            reinterpret_cast<const _Float16*>(xr16) + (size_t)node * HC + o0);
        xr0 = (float)xr01[0];
        xr1 = (float)xr01[1];
        b = rowptr[node];
        len = rowptr[node + 1] - b;
    }
    float w0a = we[o0], w0b = we[HC + o0], w0c = we[2 * HC + o0];
    float w1a = we[o1], w1b = we[HC + o1], w1c = we[2 * HC + o1];
    // att scaled by log2(e): logits in log2 domain -> raw v_exp_f32
    const float LOG2E = 1.44269504088896340736f;
    float at0f = att[o0] * LOG2E, at1f = att[o1] * LOG2E;
    hv2 at01 = pkrtz(at0f, at1f);
    const hv2 k02 = {(_Float16)0.2f, (_Float16)0.2f};

    float m_run = -1e30f, den = 0.f, acc0 = 0.f, acc1 = 0.f;

    int nk = (len + 3) >> 2;
    for (int kb = 0; kb < nk; ++kb) {
        int k0 = kb * 4;
        float L[4];
        hv2 xh[4];
        #pragma unroll
        for (int u = 0; u < 4; ++u) {
            int kk = k0 + u;
            bool v = kk < len;
            int s = b + (v ? kk : 0);
            float4 q = cefs[s];
            int src = __float_as_int(q.w);
            hv2 x2 = *reinterpret_cast<const hv2*>(xl + (size_t)src * HC + o0);
            float t0 = fmaf(q.z, w0c, fmaf(q.y, w0b, fmaf(q.x, w0a, xr0)));
            float t1 = fmaf(q.z, w1c, fmaf(q.y, w1b, fmaf(q.x, w1a, xr1)));
            hv2 s01 = x2 + pkrtz(t0, t1);
            hv2 lr01 = __builtin_elementwise_max(s01, s01 * k02);  // leaky-relu
            float partial = fmaf((float)lr01[0], at0f, (float)lr01[1] * at1f);
            #pragma unroll
            for (int mk = 1; mk < C / 2; mk <<= 1) partial += __shfl_xor(partial, mk);
            L[u] = v ? partial : -1e30f;
            xh[u] = x2;
        }
        float Lm = fmaxf(fmaxf(L[0], L[1]), fmaxf(L[2], L[3]));
        float nm = fmaxf(m_run, Lm);
        float sc = __builtin_amdgcn_exp2f(m_run - nm);
        float p0 = __builtin_amdgcn_exp2f(L[0] - nm);
        float p1 = __builtin_amdgcn_exp2f(L[1] - nm);
        float p2 = __builtin_amdgcn_exp2f(L[2] - nm);
        float p3 = __builtin_amdgcn_exp2f(L[3] - nm);
        den = den * sc + ((p0 + p1) + (p2 + p3));
        // f16 operand + f32 accumulate -> v_fma_mix_f32
        acc0 = fmaf(acc0, sc, fmaf(p0, (float)xh[0][0], fmaf(p1, (float)xh[1][0],
                    fmaf(p2, (float)xh[2][0], p3 * (float)xh[3][0]))));
        acc1 = fmaf(acc1, sc, fmaf(p0, (float)xh[0][1], fmaf(p1, (float)xh[1][1],
                    fmaf(p2, (float)xh[2][1], p3 * (float)xh[3][1]))));
        m_run = nm;
    }

    if (act) {
        float inv = 1.0f / den;  // self-loop guarantees den > 0
        float r0 = fmaxf(acc0 * inv + cb[o0], 0.f);
        float r1 = fmaxf(acc1 * inv + cb[o1], 0.f);
        *reinterpret_cast<float2*>(hout + (size_t)node * HC + o0) = make_float2(r0, r1);
    }
}

// ---------------- pooling + final linear ----------------
__global__ void k_pool(const float* __restrict__ h, const int* __restrict__ batch,
                       float* __restrict__ psum, int* __restrict__ pcnt, int N) {
    int o = threadIdx.x & 63;
    int j = threadIdx.x >> 6;
    int nb = blockIdx.x * 32;
    float acc = 0.f;
    int gcur = -1, cntacc = 0;
    for (int jj = j; jj < 32; jj += 4) {
        int node = nb + jj;
        if (node >= N) break;
        int g = batch[node];
        if (g != gcur) {
            if (gcur >= 0) {
                atomicAdd(&psum[gcur * 64 + o], acc);
                if (o == 0) atomicAdd(&pcnt[gcur], cntacc);
            }
            gcur = g; acc = 0.f; cntacc = 0;
        }
        acc += h[(size_t)node * 64 + o];
        ++cntacc;
    }
    if (gcur >= 0) {
        atomicAdd(&psum[gcur * 64 + o], acc);
        if (o == 0) atomicAdd(&pcnt[gcur], cntacc);
    }
}

__global__ void k_final(const float* __restrict__ psum, const int* __restrict__ pcnt,
                        const float* __restrict__ wlin, const float* __restrict__ blin,
                        float* __restrict__ out, int G) {
    int t = blockIdx.x * blockDim.x + threadIdx.x;
    if (t >= G * 32) return;
    int g = t / 32, j = t % 32;
    float acc = 0.f;
    for (int k = 0; k < 64; ++k) acc = fmaf(psum[g * 64 + k], wlin[k * 32 + j], acc);
    float inv = 1.0f / (float)max(pcnt[g], 1);
    out[t] = acc * inv + blin[j];
}

// ---------------- host ----------------

extern "C" void kernel_launch(void* const* d_in, const int* in_sizes, int n_in,
                              void* d_out, int out_size, void* d_ws, size_t ws_size,
                              hipStream_t stream) {
    const float* x = (const float*)d_in[0];
    const int* ei = (const int*)d_in[1];
    const float* ef = (const float*)d_in[2];
    const int* batch = (const int*)d_in[3];

    int N = in_sizes[0] / 5;
    int E = in_sizes[1] / 2;
    int G = out_size / 32;
    int Etot = E + N;
    const int* srcA = ei;
    const int* dstA = ei + E;

    char* w = (char*)d_ws;
    size_t off = 0;
    auto A = [&](size_t bytes) -> void* {
        void* p = w + off;
        off = (off + bytes + 255) & ~(size_t)255;
        return p;
    };
    // zero-init region: cnt0, fill, psum, pcnt
    int* cnt0 = (int*)A((size_t)N * 4);
    int* fill = (int*)A((size_t)N * 4);
    float* psum = (float*)A((size_t)G * 64 * 4);
    int* pcnt = (int*)A((size_t)G * 4);
    size_t zbytes = off;
    int* rowptr = (int*)A((size_t)(N + 1) * 4);
    int* part = (int*)A((size_t)64 * 4);
    float4* cefs = (float4*)A((size_t)Etot * 16);
    __half* xl16 = (__half*)A((size_t)N * 128 * 2);
    __half* xr16 = (__half*)A((size_t)N * 128 * 2);
    float* h0 = (float*)A((size_t)N * 128 * 4);
    float* h1 = (float*)A((size_t)N * 128 * 4);

    (void)hipMemsetAsync(d_ws, 0, zbytes, stream);

    dim3 B(TPB);
    k_count<<<(E + TPB - 1) / TPB, B, 0, stream>>>(dstA, cnt0, E);

    int ept = (N + 64 * TPB - 1) / (64 * TPB);
    if (ept < 4) ept = 4;
    int nb = (N + ept * TPB - 1) / (ept * TPB);
    k_scan_part<<<nb, B, 0, stream>>>(cnt0, part, N, ept);
    k_scan_top<<<1, 64, 0, stream>>>(part, rowptr, nb, N);
    k_scan_fin<<<nb, B, 0, stream>>>(cnt0, part, rowptr, N, ept);

    k_fill<<<(E + TPB - 1) / TPB, B, 0, stream>>>(srcA, dstA, ef, rowptr, fill, cefs, E);
    k_selfloop<<<(N + TPB - 1) / TPB, B, 0, stream>>>(rowptr, cnt0, cefs, N);

    float* houts[4] = {h0, h1, h0, h1};

    int nblk = (N + 31) / 32;
    const float* hin = x;
    for (int l = 0; l < 4; ++l) {
        const float* wl  = (const float*)d_in[4 + l * 7 + 0];
        const float* bl  = (const float*)d_in[4 + l * 7 + 1];
        const float* wr  = (const float*)d_in[4 + l * 7 + 2];
        const float* br  = (const float*)d_in[4 + l * 7 + 3];
        const float* we  = (const float*)d_in[4 + l * 7 + 4];
        const float* att = (const float*)d_in[4 + l * 7 + 5];
        const float* cb  = (const float*)d_in[4 + l * 7 + 6];
        int H = (l == 3) ? 2 : 4;
        int C = (l == 0) ? 16 : 32;
        int HC = H * C;

        if (l == 0)      k_lin_s<5, 64>   <<<nblk, B, 0, stream>>>(hin, wl, bl, wr, br, xl16, xr16, N);
        else if (l == 1) k_lin2<64, 128>  <<<nblk, B, 0, stream>>>(hin, wl, bl, wr, br, xl16, xr16, N);
        else if (l == 2) k_lin2<128, 128> <<<nblk, B, 0, stream>>>(hin, wl, bl, wr, br, xl16, xr16, N);
        else             k_lin2<128, 64>  <<<nblk, B, 0, stream>>>(hin, wl, bl, wr, br, xl16, xr16, N);

        int npw = 64 / (HC / 2);
        int waves = (N + npw - 1) / npw;
        int blocks = (waves + 3) / 4;
        if (H == 4 && C == 16)
            k_fused<4, 16><<<blocks, B, 0, stream>>>(rowptr, cefs, xl16, xr16,
                                                     we, att, cb, houts[l], N);
        else if (H == 4 && C == 32)
            k_fused<4, 32><<<blocks, B, 0, stream>>>(rowptr, cefs, xl16, xr16,
                                                     we, att, cb, houts[l], N);
        else
            k_fused<2, 32><<<blocks, B, 0, stream>>>(rowptr, cefs, xl16, xr16,
                                                     we, att, cb, houts[l], N);
        hin = houts[l];
    }

    k_pool<<<(N + 31) / 32, B, 0, stream>>>(hin, batch, psum, pcnt, N);
    k_final<<<(G * 32 + TPB - 1) / TPB, B, 0, stream>>>(psum, pcnt,
                                                        (const float*)d_in[32],
                                                        (const float*)d_in[33],
                                                        (float*)d_out, G);
}

// Round 12
// 442.878 us; speedup vs baseline: 1.3698x; 1.2242x over previous
//
#include <hip/hip_runtime.h>
#include <hip/hip_fp16.h>

#define TPB 256

typedef _Float16 hv2 __attribute__((ext_vector_type(2)));
typedef _Float16 f16x8 __attribute__((ext_vector_type(8)));
typedef float f32x4v __attribute__((ext_vector_type(4)));

// cvt_pkrtz returns an __fp16 vector; bit-cast to our _Float16 vector type
static __device__ __forceinline__ hv2 pkrtz(float a, float b) {
    auto t = __builtin_amdgcn_cvt_pkrtz(a, b);
    return __builtin_bit_cast(hv2, t);
}

// ---------------- CSR build ----------------

__global__ void k_count(const int* __restrict__ dstA, int* __restrict__ cnt, int E) {
    int e = blockIdx.x * blockDim.x + threadIdx.x;
    if (e >= E) return;
    atomicAdd(&cnt[dstA[e]], 1);
}

// ---- 3-phase exclusive scan of (cnt[i]+1) ----
__global__ void k_scan_part(const int* __restrict__ cnt, int* __restrict__ part,
                            int N, int ept) {
    __shared__ int sm[TPB];
    int tid = threadIdx.x;
    int beg = (blockIdx.x * TPB + tid) * ept;
    int s = 0;
    for (int u = 0; u < ept; ++u) {
        int i = beg + u;
        if (i < N) s += cnt[i] + 1;
    }
    sm[tid] = s;
    __syncthreads();
    for (int st = TPB / 2; st; st >>= 1) {
        if (tid < st) sm[tid] += sm[tid + st];
        __syncthreads();
    }
    if (tid == 0) part[blockIdx.x] = sm[0];
}

__global__ void k_scan_top(int* __restrict__ part, int* __restrict__ rowptr,
                           int nb, int N) {
    int lane = threadIdx.x & 63;
    int orig = (lane < nb) ? part[lane] : 0;
    int v = orig;
    #pragma unroll
    for (int ofs = 1; ofs < 64; ofs <<= 1) {
        int t = __shfl_up(v, ofs);
        if (lane >= ofs) v += t;
    }
    if (lane < nb) part[lane] = v - orig;
    if (lane == 63) rowptr[N] = v;
}

__global__ void k_scan_fin(const int* __restrict__ cnt, const int* __restrict__ part,
                           int* __restrict__ rowptr, int N, int ept) {
    __shared__ int wsum[TPB / 64];
    int tid = threadIdx.x;
    int lane = tid & 63, wid = tid >> 6;
    int beg = (blockIdx.x * TPB + tid) * ept;
    int s = 0;
    for (int u = 0; u < ept; ++u) {
        int i = beg + u;
        if (i < N) s += cnt[i] + 1;
    }
    int v = s;
    #pragma unroll
    for (int ofs = 1; ofs < 64; ofs <<= 1) {
        int t = __shfl_up(v, ofs);
        if (lane >= ofs) v += t;
    }
    if (lane == 63) wsum[wid] = v;
    __syncthreads();
    int woff = 0;
    for (int k = 0; k < wid; ++k) woff += wsum[k];
    int acc = (v - s) + woff + part[blockIdx.x];
    for (int u = 0; u < ept; ++u) {
        int i = beg + u;
        if (i < N) { rowptr[i] = acc; acc += cnt[i] + 1; }
    }
}

// cefs[slot] = (f0, f1, f2, bitcast(src))
__global__ void k_fill(const int* __restrict__ srcA, const int* __restrict__ dstA,
                       const float* __restrict__ ef,
                       const int* __restrict__ rowptr, int* __restrict__ fill,
                       float4* __restrict__ cefs, int E) {
    int e = blockIdx.x * blockDim.x + threadIdx.x;
    if (e >= E) return;
    int d = dstA[e];
    int pos = atomicAdd(&fill[d], 1);
    int slot = rowptr[d] + pos;
    cefs[slot] = make_float4(ef[e * 3 + 0], ef[e * 3 + 1], ef[e * 3 + 2],
                             __int_as_float(srcA[e]));
}

__global__ void k_selfloop(const int* __restrict__ rowptr, const int* __restrict__ cnt,
                           float4* __restrict__ cefs, int N) {
    int i = blockIdx.x * blockDim.x + threadIdx.x;
    if (i >= N) return;
    int b = rowptr[i];
    int c = cnt[i];
    float s0 = 0.f, s1 = 0.f, s2 = 0.f;
    for (int s = b; s < b + c; ++s) {
        float4 q = cefs[s];
        s0 += q.x; s1 += q.y; s2 += q.z;
    }
    float inv = 1.0f / (float)max(c, 1);
    cefs[b + c] = make_float4(s0 * inv, s1 * inv, s2 * inv, __int_as_float(i));
}

// ---------------- layer-0 linear (F=5): simple register-tiled ----------------
template <int F, int HC>
__global__ void k_lin_s(const float* __restrict__ xin,
                        const float* __restrict__ wl, const float* __restrict__ bl,
                        const float* __restrict__ wr, const float* __restrict__ br,
                        __half* __restrict__ xl16, __half* __restrict__ xr16, int N) {
    constexpr int OPT = HC / 16;
    __shared__ float xs[32][F + 1];
    int n0 = blockIdx.x * 32;
    int tid = threadIdx.x;

    for (int idx = tid; idx < 32 * F; idx += TPB) {
        int n = idx / F, k = idx - n * F;
        int gn = n0 + n;
        xs[n][k] = (gn < N) ? xin[(size_t)gn * F + k] : 0.f;
    }
    __syncthreads();

    int og = tid & 31;
    int ng = tid >> 5;
    int o0 = og * OPT;
    bool isL = o0 < HC;
    int col = isL ? o0 : o0 - HC;
    const float* wp = isL ? wl : wr;
    const float* bp = isL ? bl : br;
    __half* outp = isL ? xl16 : xr16;

    float acc[4][OPT];
    #pragma unroll
    for (int j = 0; j < 4; ++j)
        #pragma unroll
        for (int m = 0; m < OPT; ++m) acc[j][m] = 0.f;

    #pragma unroll
    for (int k = 0; k < F; ++k) {
        float wv[OPT];
        #pragma unroll
        for (int m = 0; m < OPT; m += 4)
            *reinterpret_cast<float4*>(&wv[m]) =
                *reinterpret_cast<const float4*>(wp + (size_t)k * HC + col + m);
        #pragma unroll
        for (int j = 0; j < 4; ++j) {
            float xv = xs[ng * 4 + j][k];
            #pragma unroll
            for (int m = 0; m < OPT; ++m) acc[j][m] = fmaf(xv, wv[m], acc[j][m]);
        }
    }

    float bias[OPT];
    #pragma unroll
    for (int m = 0; m < OPT; ++m) bias[m] = bp[col + m];

    #pragma unroll
    for (int j = 0; j < 4; ++j) {
        int node = n0 + ng * 4 + j;
        if (node >= N) continue;
        #pragma unroll
        for (int m = 0; m < OPT; m += 2) {
            __half2 hv = __half2(__float2half(acc[j][m] + bias[m]),
                                 __float2half(acc[j][m + 1] + bias[m + 1]));
            *reinterpret_cast<__half2*>(outp + (size_t)node * HC + col + m) = hv;
        }
    }
}

// ---------------- big linear layers: MFMA fp16 GEMM ----------------
// Block: 64 nodes x W2 (=2*HC) outputs, 4 waves. Wave: 4 row-tiles x CTW col-tiles
// of 16x16 via mfma_f32_16x16x32_f16. x staged fp16 once; W chunk staged fp16
// transposed per K=32 chunk. Bias folded into accumulator init.
template <int F, int HC>
__global__ void k_lin_mfma(const float* __restrict__ xin,
                           const float* __restrict__ wl, const float* __restrict__ bl,
                           const float* __restrict__ wr, const float* __restrict__ br,
                           __half* __restrict__ xl16, __half* __restrict__ xr16, int N) {
    constexpr int W2 = 2 * HC;       // 256 or 128
    constexpr int NT = 64;           // nodes per block
    constexpr int KC = 32;           // k chunk (one MFMA K)
    constexpr int CT = W2 / 16;      // col tiles
    constexpr int CTW = CT / 4;      // col tiles per wave (4 or 2)
    constexpr int C4 = W2 / 4;
    __shared__ _Float16 xs[NT][F + 8];
    __shared__ _Float16 wsT[W2][KC + 8];

    int n0 = blockIdx.x * NT;
    int tid = threadIdx.x;
    int lane = tid & 63;
    int wv = tid >> 6;
    int lane15 = lane & 15;
    int kb = (lane >> 4) * 8;

    // stage x as fp16 (float4 reads, 8B LDS writes)
    for (int idx = tid * 4; idx < NT * F; idx += TPB * 4) {
        int n = idx / F, k = idx - n * F;
        int gn = n0 + n;
        float4 v = (gn < N) ? *reinterpret_cast<const float4*>(xin + (size_t)gn * F + k)
                            : make_float4(0.f, 0.f, 0.f, 0.f);
        unsigned int lo = __builtin_bit_cast(unsigned int, pkrtz(v.x, v.y));
        unsigned int hi = __builtin_bit_cast(unsigned int, pkrtz(v.z, v.w));
        *reinterpret_cast<uint2*>(&xs[n][k]) = make_uint2(lo, hi);
    }

    // accumulators init with bias (col fixed per lane per tile; all 4 rows share it)
    f32x4v acc[4][CTW];
    #pragma unroll
    for (int t = 0; t < CTW; ++t) {
        int col = (wv * CTW + t) * 16 + lane15;
        float bv = (col < HC) ? bl[col] : br[col - HC];
        #pragma unroll
        for (int tr = 0; tr < 4; ++tr) acc[tr][t] = (f32x4v){bv, bv, bv, bv};
    }

    for (int kc = 0; kc < F; kc += KC) {
        __syncthreads();  // xs ready (1st) / prev wsT reads done
        // stage W chunk transposed as fp16: k-pairs packed -> b32 writes
        for (int idx = tid; idx < (KC / 2) * C4; idx += TPB) {
            int k2 = idx / C4;
            int c = (idx - k2 * C4) * 4;
            int k = kc + k2 * 2;
            float4 r0, r1;
            if (c < HC) {
                r0 = *reinterpret_cast<const float4*>(wl + (size_t)k * HC + c);
                r1 = *reinterpret_cast<const float4*>(wl + (size_t)(k + 1) * HC + c);
            } else {
                int cc = c - HC;
                r0 = *reinterpret_cast<const float4*>(wr + (size_t)k * HC + cc);
                r1 = *reinterpret_cast<const float4*>(wr + (size_t)(k + 1) * HC + cc);
            }
            int kk = k2 * 2;
            *reinterpret_cast<unsigned int*>(&wsT[c + 0][kk]) = __builtin_bit_cast(unsigned int, pkrtz(r0.x, r1.x));
            *reinterpret_cast<unsigned int*>(&wsT[c + 1][kk]) = __builtin_bit_cast(unsigned int, pkrtz(r0.y, r1.y));
            *reinterpret_cast<unsigned int*>(&wsT[c + 2][kk]) = __builtin_bit_cast(unsigned int, pkrtz(r0.z, r1.z));
            *reinterpret_cast<unsigned int*>(&wsT[c + 3][kk]) = __builtin_bit_cast(unsigned int, pkrtz(r0.w, r1.w));
        }
        __syncthreads();

        f16x8 a[4];
        #pragma unroll
        for (int tr = 0; tr < 4; ++tr)
            a[tr] = *reinterpret_cast<const f16x8*>(&xs[tr * 16 + lane15][kc + kb]);
        #pragma unroll
        for (int t = 0; t < CTW; ++t) {
            int col = (wv * CTW + t) * 16 + lane15;
            f16x8 bfr = *reinterpret_cast<const f16x8*>(&wsT[col][kb]);
            #pragma unroll
            for (int tr = 0; tr < 4; ++tr)
                acc[tr][t] = __builtin_amdgcn_mfma_f32_16x16x32_f16(a[tr], bfr, acc[tr][t], 0, 0, 0);
        }
    }

    // epilogue: D layout col=lane&15, row=(lane>>4)*4+j  (HW-verified)
    #pragma unroll
    for (int t = 0; t < CTW; ++t) {
        int col = (wv * CTW + t) * 16 + lane15;
        bool isL = col < HC;
        __half* outp = isL ? xl16 : xr16;
        int c = isL ? col : col - HC;
        #pragma unroll
        for (int tr = 0; tr < 4; ++tr) {
            #pragma unroll
            for (int j = 0; j < 4; ++j) {
                int node = n0 + tr * 16 + (lane >> 4) * 4 + j;
                if (node < N) outp[(size_t)node * HC + c] = __float2half(acc[tr][t][j]);
            }
        }
    }
}

// ---------------- fused GATv2 attention + aggregation ----------------
// Packed-f16 edge math: pk_add / pk_max, f32 edge-term + softmax state.
template <int H, int C>
__global__ void k_fused(const int* __restrict__ rowptr,
                        const float4* __restrict__ cefs,
                        const __half* __restrict__ xl16, const __half* __restrict__ xr16,
                        const float* __restrict__ we, const float* __restrict__ att,
                        const float* __restrict__ cb, float* __restrict__ hout, int N) {
    constexpr int HC = H * C;
    constexpr int PAIRS = HC / 2;
    constexpr int NPW = 64 / PAIRS;
    const _Float16* xl = reinterpret_cast<const _Float16*>(xl16);
    int wave = (blockIdx.x * blockDim.x + threadIdx.x) >> 6;
    int lane = threadIdx.x & 63;
    int g = lane / PAIRS;
    int p = lane % PAIRS;
    int node = wave * NPW + g;
    bool act = node < N;

    int o0 = 2 * p, o1 = 2 * p + 1;
    float xr0 = 0.f, xr1 = 0.f;
    int b = 0, len = 0;
    if (act) {
        hv2 xr01 = *reinterpret_cast<const hv2*>(
            reinterpret_cast<const _Float16*>(xr16) + (size_t)node * HC + o0);
        xr0 = (float)xr01[0];
        xr1 = (float)xr01[1];
        b = rowptr[node];
        len = rowptr[node + 1] - b;
    }
    float w0a = we[o0], w0b = we[HC + o0], w0c = we[2 * HC + o0];
    float w1a = we[o1], w1b = we[HC + o1], w1c = we[2 * HC + o1];
    const float LOG2E = 1.44269504088896340736f;
    float at0f = att[o0] * LOG2E, at1f = att[o1] * LOG2E;
    const hv2 k02 = {(_Float16)0.2f, (_Float16)0.2f};

    float m_run = -1e30f, den = 0.f, acc0 = 0.f, acc1 = 0.f;

    int nk = (len + 3) >> 2;
    for (int kb = 0; kb < nk; ++kb) {
        int k0 = kb * 4;
        float L[4];
        hv2 xh[4];
        #pragma unroll
        for (int u = 0; u < 4; ++u) {
            int kk = k0 + u;
            bool v = kk < len;
            int s = b + (v ? kk : 0);
            float4 q = cefs[s];
            int src = __float_as_int(q.w);
            hv2 x2 = *reinterpret_cast<const hv2*>(xl + (size_t)src * HC + o0);
            float t0 = fmaf(q.z, w0c, fmaf(q.y, w0b, fmaf(q.x, w0a, xr0)));
            float t1 = fmaf(q.z, w1c, fmaf(q.y, w1b, fmaf(q.x, w1a, xr1)));
            hv2 s01 = x2 + pkrtz(t0, t1);
            hv2 lr01 = __builtin_elementwise_max(s01, s01 * k02);  // leaky-relu
            float partial = fmaf((float)lr01[0], at0f, (float)lr01[1] * at1f);
            #pragma unroll
            for (int mk = 1; mk < C / 2; mk <<= 1) partial += __shfl_xor(partial, mk);
            L[u] = v ? partial : -1e30f;
            xh[u] = x2;
        }
        float Lm = fmaxf(fmaxf(L[0], L[1]), fmaxf(L[2], L[3]));
        float nm = fmaxf(m_run, Lm);
        float sc = __builtin_amdgcn_exp2f(m_run - nm);
        float p0 = __builtin_amdgcn_exp2f(L[0] - nm);
        float p1 = __builtin_amdgcn_exp2f(L[1] - nm);
        float p2 = __builtin_amdgcn_exp2f(L[2] - nm);
        float p3 = __builtin_amdgcn_exp2f(L[3] - nm);
        den = den * sc + ((p0 + p1) + (p2 + p3));
        acc0 = fmaf(acc0, sc, fmaf(p0, (float)xh[0][0], fmaf(p1, (float)xh[1][0],
                    fmaf(p2, (float)xh[2][0], p3 * (float)xh[3][0]))));
        acc1 = fmaf(acc1, sc, fmaf(p0, (float)xh[0][1], fmaf(p1, (float)xh[1][1],
                    fmaf(p2, (float)xh[2][1], p3 * (float)xh[3][1]))));
        m_run = nm;
    }

    if (act) {
        float inv = 1.0f / den;  // self-loop guarantees den > 0
        float r0 = fmaxf(acc0 * inv + cb[o0], 0.f);
        float r1 = fmaxf(acc1 * inv + cb[o1], 0.f);
        *reinterpret_cast<float2*>(hout + (size_t)node * HC + o0) = make_float2(r0, r1);
    }
}

// ---------------- pooling + final linear ----------------
__global__ void k_pool(const float* __restrict__ h, const int* __restrict__ batch,
                       float* __restrict__ psum, int* __restrict__ pcnt, int N) {
    int o = threadIdx.x & 63;
    int j = threadIdx.x >> 6;
    int nb = blockIdx.x * 32;
    float acc = 0.f;
    int gcur = -1, cntacc = 0;
    for (int jj = j; jj < 32; jj += 4) {
        int node = nb + jj;
        if (node >= N) break;
        int g = batch[node];
        if (g != gcur) {
            if (gcur >= 0) {
                atomicAdd(&psum[gcur * 64 + o], acc);
                if (o == 0) atomicAdd(&pcnt[gcur], cntacc);
            }
            gcur = g; acc = 0.f; cntacc = 0;
        }
        acc += h[(size_t)node * 64 + o];
        ++cntacc;
    }
    if (gcur >= 0) {
        atomicAdd(&psum[gcur * 64 + o], acc);
        if (o == 0) atomicAdd(&pcnt[gcur], cntacc);
    }
}

__global__ void k_final(const float* __restrict__ psum, const int* __restrict__ pcnt,
                        const float* __restrict__ wlin, const float* __restrict__ blin,
                        float* __restrict__ out, int G) {
    int t = blockIdx.x * blockDim.x + threadIdx.x;
    if (t >= G * 32) return;
    int g = t / 32, j = t % 32;
    float acc = 0.f;
    for (int k = 0; k < 64; ++k) acc = fmaf(psum[g * 64 + k], wlin[k * 32 + j], acc);
    float inv = 1.0f / (float)max(pcnt[g], 1);
    out[t] = acc * inv + blin[j];
}

// ---------------- host ----------------

extern "C" void kernel_launch(void* const* d_in, const int* in_sizes, int n_in,
                              void* d_out, int out_size, void* d_ws, size_t ws_size,
                              hipStream_t stream) {
    const float* x = (const float*)d_in[0];
    const int* ei = (const int*)d_in[1];
    const float* ef = (const float*)d_in[2];
    const int* batch = (const int*)d_in[3];

    int N = in_sizes[0] / 5;
    int E = in_sizes[1] / 2;
    int G = out_size / 32;
    int Etot = E + N;
    const int* srcA = ei;
    const int* dstA = ei + E;

    char* w = (char*)d_ws;
    size_t off = 0;
    auto A = [&](size_t bytes) -> void* {
        void* p = w + off;
        off = (off + bytes + 255) & ~(size_t)255;
        return p;
    };
    // zero-init region: cnt0, fill, psum, pcnt
    int* cnt0 = (int*)A((size_t)N * 4);
    int* fill = (int*)A((size_t)N * 4);
    float* psum = (float*)A((size_t)G * 64 * 4);
    int* pcnt = (int*)A((size_t)G * 4);
    size_t zbytes = off;
    int* rowptr = (int*)A((size_t)(N + 1) * 4);
    int* part = (int*)A((size_t)64 * 4);
    float4* cefs = (float4*)A((size_t)Etot * 16);
    __half* xl16 = (__half*)A((size_t)N * 128 * 2);
    __half* xr16 = (__half*)A((size_t)N * 128 * 2);
    float* h0 = (float*)A((size_t)N * 128 * 4);
    float* h1 = (float*)A((size_t)N * 128 * 4);

    (void)hipMemsetAsync(d_ws, 0, zbytes, stream);

    dim3 B(TPB);
    k_count<<<(E + TPB - 1) / TPB, B, 0, stream>>>(dstA, cnt0, E);

    int ept = (N + 64 * TPB - 1) / (64 * TPB);
    if (ept < 4) ept = 4;
    int nb = (N + ept * TPB - 1) / (ept * TPB);
    k_scan_part<<<nb, B, 0, stream>>>(cnt0, part, N, ept);
    k_scan_top<<<1, 64, 0, stream>>>(part, rowptr, nb, N);
    k_scan_fin<<<nb, B, 0, stream>>>(cnt0, part, rowptr, N, ept);

    k_fill<<<(E + TPB - 1) / TPB, B, 0, stream>>>(srcA, dstA, ef, rowptr, fill, cefs, E);
    k_selfloop<<<(N + TPB - 1) / TPB, B, 0, stream>>>(rowptr, cnt0, cefs, N);

    float* houts[4] = {h0, h1, h0, h1};

    int nblk = (N + 31) / 32;
    int nblk64 = (N + 63) / 64;
    const float* hin = x;
    for (int l = 0; l < 4; ++l) {
        const float* wl  = (const float*)d_in[4 + l * 7 + 0];
        const float* bl  = (const float*)d_in[4 + l * 7 + 1];
        const float* wr  = (const float*)d_in[4 + l * 7 + 2];
        const float* br  = (const float*)d_in[4 + l * 7 + 3];
        const float* we  = (const float*)d_in[4 + l * 7 + 4];
        const float* att = (const float*)d_in[4 + l * 7 + 5];
        const float* cb  = (const float*)d_in[4 + l * 7 + 6];
        int H = (l == 3) ? 2 : 4;
        int C = (l == 0) ? 16 : 32;
        int HC = H * C;

        if (l == 0)      k_lin_s<5, 64>      <<<nblk, B, 0, stream>>>(hin, wl, bl, wr, br, xl16, xr16, N);
        else if (l == 1) k_lin_mfma<64, 128> <<<nblk64, B, 0, stream>>>(hin, wl, bl, wr, br, xl16, xr16, N);
        else if (l == 2) k_lin_mfma<128, 128><<<nblk64, B, 0, stream>>>(hin, wl, bl, wr, br, xl16, xr16, N);
        else             k_lin_mfma<128, 64> <<<nblk64, B, 0, stream>>>(hin, wl, bl, wr, br, xl16, xr16, N);

        int npw = 64 / (HC / 2);
        int waves = (N + npw - 1) / npw;
        int blocks = (waves + 3) / 4;
        if (H == 4 && C == 16)
            k_fused<4, 16><<<blocks, B, 0, stream>>>(rowptr, cefs, xl16, xr16,
                                                     we, att, cb, houts[l], N);
        else if (H == 4 && C == 32)
            k_fused<4, 32><<<blocks, B, 0, stream>>>(rowptr, cefs, xl16, xr16,
                                                     we, att, cb, houts[l], N);
        else
            k_fused<2, 32><<<blocks, B, 0, stream>>>(rowptr, cefs, xl16, xr16,
                                                     we, att, cb, houts[l], N);
        hin = houts[l];
    }

    k_pool<<<(N + 31) / 32, B, 0, stream>>>(hin, batch, psum, pcnt, N);
    k_final<<<(G * 32 + TPB - 1) / TPB, B, 0, stream>>>(psum, pcnt,
                                                        (const float*)d_in[32],
                                                        (const float*)d_in[33],
                                                        (float*)d_out, G);
}

// Round 14
// 432.179 us; speedup vs baseline: 1.4037x; 1.0248x over previous
//
#include <hip/hip_runtime.h>
#include <hip/hip_fp16.h>

#define TPB 256

typedef _Float16 hv2 __attribute__((ext_vector_type(2)));
typedef _Float16 f16x8 __attribute__((ext_vector_type(8)));
typedef float f32x4v __attribute__((ext_vector_type(4)));

// cvt_pkrtz returns an __fp16 vector; bit-cast to our _Float16 vector type
static __device__ __forceinline__ hv2 pkrtz(float a, float b) {
    auto t = __builtin_amdgcn_cvt_pkrtz(a, b);
    return __builtin_bit_cast(hv2, t);
}

// VALU DPP add: x += x[permuted lane] (row-local). CTRL is a compile-time imm.
template <int CTRL>
static __device__ __forceinline__ float dpp_add(float x) {
    int xi = __builtin_bit_cast(int, x);
    int yi = __builtin_amdgcn_update_dpp(0, xi, CTRL, 0xf, 0xf, true);
    return x + __builtin_bit_cast(float, yi);
}

// butterfly sum over SPAN lanes (SPAN = 8 or 16, within a DPP row of 16)
template <int SPAN>
static __device__ __forceinline__ float dpp_reduce(float x) {
    x = dpp_add<0xB1>(x);                     // quad_perm xor1
    x = dpp_add<0x4E>(x);                     // quad_perm xor2
    x = dpp_add<0x141>(x);                    // row_half_mirror == lane^7
    if constexpr (SPAN >= 16) x = dpp_add<0x140>(x);  // row_mirror == lane^15
    return x;
}

// ---------------- CSR build ----------------

__global__ void k_count(const int* __restrict__ dstA, int* __restrict__ cnt, int E) {
    int e = blockIdx.x * blockDim.x + threadIdx.x;
    if (e >= E) return;
    atomicAdd(&cnt[dstA[e]], 1);
}

// ---- 3-phase exclusive scan of (cnt[i]+1) ----
__global__ void k_scan_part(const int* __restrict__ cnt, int* __restrict__ part,
                            int N, int ept) {
    __shared__ int sm[TPB];
    int tid = threadIdx.x;
    int beg = (blockIdx.x * TPB + tid) * ept;
    int s = 0;
    for (int u = 0; u < ept; ++u) {
        int i = beg + u;
        if (i < N) s += cnt[i] + 1;
    }
    sm[tid] = s;
    __syncthreads();
    for (int st = TPB / 2; st; st >>= 1) {
        if (tid < st) sm[tid] += sm[tid + st];
        __syncthreads();
    }
    if (tid == 0) part[blockIdx.x] = sm[0];
}

__global__ void k_scan_top(int* __restrict__ part, int* __restrict__ rowptr,
                           int nb, int N) {
    int lane = threadIdx.x & 63;
    int orig = (lane < nb) ? part[lane] : 0;
    int v = orig;
    #pragma unroll
    for (int ofs = 1; ofs < 64; ofs <<= 1) {
        int t = __shfl_up(v, ofs);
        if (lane >= ofs) v += t;
    }
    if (lane < nb) part[lane] = v - orig;
    if (lane == 63) rowptr[N] = v;
}

__global__ void k_scan_fin(const int* __restrict__ cnt, const int* __restrict__ part,
                           int* __restrict__ rowptr, int N, int ept) {
    __shared__ int wsum[TPB / 64];
    int tid = threadIdx.x;
    int lane = tid & 63, wid = tid >> 6;
    int beg = (blockIdx.x * TPB + tid) * ept;
    int s = 0;
    for (int u = 0; u < ept; ++u) {
        int i = beg + u;
        if (i < N) s += cnt[i] + 1;
    }
    int v = s;
    #pragma unroll
    for (int ofs = 1; ofs < 64; ofs <<= 1) {
        int t = __shfl_up(v, ofs);
        if (lane >= ofs) v += t;
    }
    if (lane == 63) wsum[wid] = v;
    __syncthreads();
    int woff = 0;
    for (int k = 0; k < wid; ++k) woff += wsum[k];
    int acc = (v - s) + woff + part[blockIdx.x];
    for (int u = 0; u < ept; ++u) {
        int i = beg + u;
        if (i < N) { rowptr[i] = acc; acc += cnt[i] + 1; }
    }
}

// cefs[slot] = (f0, f1, f2, bitcast(src))
__global__ void k_fill(const int* __restrict__ srcA, const int* __restrict__ dstA,
                       const float* __restrict__ ef,
                       const int* __restrict__ rowptr, int* __restrict__ fill,
                       float4* __restrict__ cefs, int E) {
    int e = blockIdx.x * blockDim.x + threadIdx.x;
    if (e >= E) return;
    int d = dstA[e];
    int pos = atomicAdd(&fill[d], 1);
    int slot = rowptr[d] + pos;
    cefs[slot] = make_float4(ef[e * 3 + 0], ef[e * 3 + 1], ef[e * 3 + 2],
                             __int_as_float(srcA[e]));
}

__global__ void k_selfloop(const int* __restrict__ rowptr, const int* __restrict__ cnt,
                           float4* __restrict__ cefs, int N) {
    int i = blockIdx.x * blockDim.x + threadIdx.x;
    if (i >= N) return;
    int b = rowptr[i];
    int c = cnt[i];
    float s0 = 0.f, s1 = 0.f, s2 = 0.f;
    for (int s = b; s < b + c; ++s) {
        float4 q = cefs[s];
        s0 += q.x; s1 += q.y; s2 += q.z;
    }
    float inv = 1.0f / (float)max(c, 1);
    cefs[b + c] = make_float4(s0 * inv, s1 * inv, s2 * inv, __int_as_float(i));
}

// ---------------- layer-0 linear (F=5): simple register-tiled ----------------
template <int F, int HC>
__global__ void k_lin_s(const float* __restrict__ xin,
                        const float* __restrict__ wl, const float* __restrict__ bl,
                        const float* __restrict__ wr, const float* __restrict__ br,
                        __half* __restrict__ xl16, __half* __restrict__ xr16, int N) {
    constexpr int OPT = HC / 16;
    __shared__ float xs[32][F + 1];
    int n0 = blockIdx.x * 32;
    int tid = threadIdx.x;

    for (int idx = tid; idx < 32 * F; idx += TPB) {
        int n = idx / F, k = idx - n * F;
        int gn = n0 + n;
        xs[n][k] = (gn < N) ? xin[(size_t)gn * F + k] : 0.f;
    }
    __syncthreads();

    int og = tid & 31;
    int ng = tid >> 5;
    int o0 = og * OPT;
    bool isL = o0 < HC;
    int col = isL ? o0 : o0 - HC;
    const float* wp = isL ? wl : wr;
    const float* bp = isL ? bl : br;
    __half* outp = isL ? xl16 : xr16;

    float acc[4][OPT];
    #pragma unroll
    for (int j = 0; j < 4; ++j)
        #pragma unroll
        for (int m = 0; m < OPT; ++m) acc[j][m] = 0.f;

    #pragma unroll
    for (int k = 0; k < F; ++k) {
        float wv[OPT];
        #pragma unroll
        for (int m = 0; m < OPT; m += 4)
            *reinterpret_cast<float4*>(&wv[m]) =
                *reinterpret_cast<const float4*>(wp + (size_t)k * HC + col + m);
        #pragma unroll
        for (int j = 0; j < 4; ++j) {
            float xv = xs[ng * 4 + j][k];
            #pragma unroll
            for (int m = 0; m < OPT; ++m) acc[j][m] = fmaf(xv, wv[m], acc[j][m]);
        }
    }

    float bias[OPT];
    #pragma unroll
    for (int m = 0; m < OPT; ++m) bias[m] = bp[col + m];

    #pragma unroll
    for (int j = 0; j < 4; ++j) {
        int node = n0 + ng * 4 + j;
        if (node >= N) continue;
        #pragma unroll
        for (int m = 0; m < OPT; m += 2) {
            __half2 hv = __half2(__float2half(acc[j][m] + bias[m]),
                                 __float2half(acc[j][m + 1] + bias[m + 1]));
            *reinterpret_cast<__half2*>(outp + (size_t)node * HC + col + m) = hv;
        }
    }
}

// ---------------- big linear layers: MFMA fp16 GEMM ----------------
template <int F, int HC>
__global__ void k_lin_mfma(const float* __restrict__ xin,
                           const float* __restrict__ wl, const float* __restrict__ bl,
                           const float* __restrict__ wr, const float* __restrict__ br,
                           __half* __restrict__ xl16, __half* __restrict__ xr16, int N) {
    constexpr int W2 = 2 * HC;
    constexpr int NT = 64;
    constexpr int KC = 32;
    constexpr int CT = W2 / 16;
    constexpr int CTW = CT / 4;
    constexpr int C4 = W2 / 4;
    __shared__ _Float16 xs[NT][F + 8];
    __shared__ _Float16 wsT[W2][KC + 8];

    int n0 = blockIdx.x * NT;
    int tid = threadIdx.x;
    int lane = tid & 63;
    int wv = tid >> 6;
    int lane15 = lane & 15;
    int kb = (lane >> 4) * 8;

    for (int idx = tid * 4; idx < NT * F; idx += TPB * 4) {
        int n = idx / F, k = idx - n * F;
        int gn = n0 + n;
        float4 v = (gn < N) ? *reinterpret_cast<const float4*>(xin + (size_t)gn * F + k)
                            : make_float4(0.f, 0.f, 0.f, 0.f);
        unsigned int lo = __builtin_bit_cast(unsigned int, pkrtz(v.x, v.y));
        unsigned int hi = __builtin_bit_cast(unsigned int, pkrtz(v.z, v.w));
        *reinterpret_cast<uint2*>(&xs[n][k]) = make_uint2(lo, hi);
    }

    f32x4v acc[4][CTW];
    #pragma unroll
    for (int t = 0; t < CTW; ++t) {
        int col = (wv * CTW + t) * 16 + lane15;
        float bv = (col < HC) ? bl[col] : br[col - HC];
        #pragma unroll
        for (int tr = 0; tr < 4; ++tr) acc[tr][t] = (f32x4v){bv, bv, bv, bv};
    }

    for (int kc = 0; kc < F; kc += KC) {
        __syncthreads();
        for (int idx = tid; idx < (KC / 2) * C4; idx += TPB) {
            int k2 = idx / C4;
            int c = (idx - k2 * C4) * 4;
            int k = kc + k2 * 2;
            float4 r0, r1;
            if (c < HC) {
                r0 = *reinterpret_cast<const float4*>(wl + (size_t)k * HC + c);
                r1 = *reinterpret_cast<const float4*>(wl + (size_t)(k + 1) * HC + c);
            } else {
                int cc = c - HC;
                r0 = *reinterpret_cast<const float4*>(wr + (size_t)k * HC + cc);
                r1 = *reinterpret_cast<const float4*>(wr + (size_t)(k + 1) * HC + cc);
            }
            int kk = k2 * 2;
            *reinterpret_cast<unsigned int*>(&wsT[c + 0][kk]) = __builtin_bit_cast(unsigned int, pkrtz(r0.x, r1.x));
            *reinterpret_cast<unsigned int*>(&wsT[c + 1][kk]) = __builtin_bit_cast(unsigned int, pkrtz(r0.y, r1.y));
            *reinterpret_cast<unsigned int*>(&wsT[c + 2][kk]) = __builtin_bit_cast(unsigned int, pkrtz(r0.z, r1.z));
            *reinterpret_cast<unsigned int*>(&wsT[c + 3][kk]) = __builtin_bit_cast(unsigned int, pkrtz(r0.w, r1.w));
        }
        __syncthreads();

        f16x8 a[4];
        #pragma unroll
        for (int tr = 0; tr < 4; ++tr)
            a[tr] = *reinterpret_cast<const f16x8*>(&xs[tr * 16 + lane15][kc + kb]);
        #pragma unroll
        for (int t = 0; t < CTW; ++t) {
            int col = (wv * CTW + t) * 16 + lane15;
            f16x8 bfr = *reinterpret_cast<const f16x8*>(&wsT[col][kb]);
            #pragma unroll
            for (int tr = 0; tr < 4; ++tr)
                acc[tr][t] = __builtin_amdgcn_mfma_f32_16x16x32_f16(a[tr], bfr, acc[tr][t], 0, 0, 0);
        }
    }

    #pragma unroll
    for (int t = 0; t < CTW; ++t) {
        int col = (wv * CTW + t) * 16 + lane15;
        bool isL = col < HC;
        __half* outp = isL ? xl16 : xr16;
        int c = isL ? col : col - HC;
        #pragma unroll
        for (int tr = 0; tr < 4; ++tr) {
            #pragma unroll
            for (int j = 0; j < 4; ++j) {
                int node = n0 + tr * 16 + (lane >> 4) * 4 + j;
                if (node < N) outp[(size_t)node * HC + c] = __float2half(acc[tr][t][j]);
            }
        }
    }
}

// ---------------- fused GATv2 attention + aggregation ----------------
// Packed-f16 edge math + DPP butterfly reduce (pure VALU, no LDS pipe).
template <int H, int C>
__global__ void k_fused(const int* __restrict__ rowptr,
                        const float4* __restrict__ cefs,
                        const __half* __restrict__ xl16, const __half* __restrict__ xr16,
                        const float* __restrict__ we, const float* __restrict__ att,
                        const float* __restrict__ cb, float* __restrict__ hout, int N) {
    constexpr int HC = H * C;
    constexpr int PAIRS = HC / 2;
    constexpr int NPW = 64 / PAIRS;
    constexpr int SPAN = C / 2;  // lanes per head (8 or 16)
    const _Float16* xl = reinterpret_cast<const _Float16*>(xl16);
    int wave = (blockIdx.x * blockDim.x + threadIdx.x) >> 6;
    int lane = threadIdx.x & 63;
    int g = lane / PAIRS;
    int p = lane % PAIRS;
    int node = wave * NPW + g;
    bool act = node < N;

    int o0 = 2 * p, o1 = 2 * p + 1;
    float xr0 = 0.f, xr1 = 0.f;
    int b = 0, len = 0;
    if (act) {
        hv2 xr01 = *reinterpret_cast<const hv2*>(
            reinterpret_cast<const _Float16*>(xr16) + (size_t)node * HC + o0);
        xr0 = (float)xr01[0];
        xr1 = (float)xr01[1];
        b = rowptr[node];
        len = rowptr[node + 1] - b;
    }
    float w0a = we[o0], w0b = we[HC + o0], w0c = we[2 * HC + o0];
    float w1a = we[o1], w1b = we[HC + o1], w1c = we[2 * HC + o1];
    const float LOG2E = 1.44269504088896340736f;
    float at0f = att[o0] * LOG2E, at1f = att[o1] * LOG2E;
    const hv2 k02 = {(_Float16)0.2f, (_Float16)0.2f};

    float m_run = -1e30f, den = 0.f, acc0 = 0.f, acc1 = 0.f;

    int nk = (len + 3) >> 2;
    for (int kb = 0; kb < nk; ++kb) {
        int k0 = kb * 4;
        float L[4];
        hv2 xh[4];
        #pragma unroll
        for (int u = 0; u < 4; ++u) {
            int kk = k0 + u;
            bool v = kk < len;
            int s = b + (v ? kk : 0);
            float4 q = cefs[s];
            int src = __float_as_int(q.w);
            hv2 x2 = *reinterpret_cast<const hv2*>(xl + (size_t)src * HC + o0);
            float t0 = fmaf(q.z, w0c, fmaf(q.y, w0b, fmaf(q.x, w0a, xr0)));
            float t1 = fmaf(q.z, w1c, fmaf(q.y, w1b, fmaf(q.x, w1a, xr1)));
            hv2 s01 = x2 + pkrtz(t0, t1);
            hv2 lr01 = __builtin_elementwise_max(s01, s01 * k02);  // leaky-relu
            float partial = fmaf((float)lr01[0], at0f, (float)lr01[1] * at1f);
            partial = dpp_reduce<SPAN>(partial);   // VALU DPP butterfly
            L[u] = v ? partial : -1e30f;
            xh[u] = x2;
        }
        float Lm = fmaxf(fmaxf(L[0], L[1]), fmaxf(L[2], L[3]));
        float nm = fmaxf(m_run, Lm);
        float sc = __builtin_amdgcn_exp2f(m_run - nm);
        float p0 = __builtin_amdgcn_exp2f(L[0] - nm);
        float p1 = __builtin_amdgcn_exp2f(L[1] - nm);
        float p2 = __builtin_amdgcn_exp2f(L[2] - nm);
        float p3 = __builtin_amdgcn_exp2f(L[3] - nm);
        den = den * sc + ((p0 + p1) + (p2 + p3));
        acc0 = fmaf(acc0, sc, fmaf(p0, (float)xh[0][0], fmaf(p1, (float)xh[1][0],
                    fmaf(p2, (float)xh[2][0], p3 * (float)xh[3][0]))));
        acc1 = fmaf(acc1, sc, fmaf(p0, (float)xh[0][1], fmaf(p1, (float)xh[1][1],
                    fmaf(p2, (float)xh[2][1], p3 * (float)xh[3][1]))));
        m_run = nm;
    }

    if (act) {
        float inv = 1.0f / den;  // self-loop guarantees den > 0
        float r0 = fmaxf(acc0 * inv + cb[o0], 0.f);
        float r1 = fmaxf(acc1 * inv + cb[o1], 0.f);
        *reinterpret_cast<float2*>(hout + (size_t)node * HC + o0) = make_float2(r0, r1);
    }
}

// ---------------- pooling + final linear ----------------
__global__ void k_pool(const float* __restrict__ h, const int* __restrict__ batch,
                       float* __restrict__ psum, int* __restrict__ pcnt, int N) {
    int o = threadIdx.x & 63;
    int j = threadIdx.x >> 6;
    int nb = blockIdx.x * 32;
    float acc = 0.f;
    int gcur = -1, cntacc = 0;
    for (int jj = j; jj < 32; jj += 4) {
        int node = nb + jj;
        if (node >= N) break;
        int g = batch[node];
        if (g != gcur) {
            if (gcur >= 0) {
                atomicAdd(&psum[gcur * 64 + o], acc);
                if (o == 0) atomicAdd(&pcnt[gcur], cntacc);
            }
            gcur = g; acc = 0.f; cntacc = 0;
        }
        acc += h[(size_t)node * 64 + o];
        ++cntacc;
    }
    if (gcur >= 0) {
        atomicAdd(&psum[gcur * 64 + o], acc);
        if (o == 0) atomicAdd(&pcnt[gcur], cntacc);
    }
}

__global__ void k_final(const float* __restrict__ psum, const int* __restrict__ pcnt,
                        const float* __restrict__ wlin, const float* __restrict__ blin,
                        float* __restrict__ out, int G) {
    int t = blockIdx.x * blockDim.x + threadIdx.x;
    if (t >= G * 32) return;
    int g = t / 32, j = t % 32;
    float acc = 0.f;
    for (int k = 0; k < 64; ++k) acc = fmaf(psum[g * 64 + k], wlin[k * 32 + j], acc);
    float inv = 1.0f / (float)max(pcnt[g], 1);
    out[t] = acc * inv + blin[j];
}

// ---------------- host ----------------

extern "C" void kernel_launch(void* const* d_in, const int* in_sizes, int n_in,
                              void* d_out, int out_size, void* d_ws, size_t ws_size,
                              hipStream_t stream) {
    const float* x = (const float*)d_in[0];
    const int* ei = (const int*)d_in[1];
    const float* ef = (const float*)d_in[2];
    const int* batch = (const int*)d_in[3];

    int N = in_sizes[0] / 5;
    int E = in_sizes[1] / 2;
    int G = out_size / 32;
    int Etot = E + N;
    const int* srcA = ei;
    const int* dstA = ei + E;

    char* w = (char*)d_ws;
    size_t off = 0;
    auto A = [&](size_t bytes) -> void* {
        void* p = w + off;
        off = (off + bytes + 255) & ~(size_t)255;
        return p;
    };
    // zero-init region: cnt0, fill, psum, pcnt
    int* cnt0 = (int*)A((size_t)N * 4);
    int* fill = (int*)A((size_t)N * 4);
    float* psum = (float*)A((size_t)G * 64 * 4);
    int* pcnt = (int*)A((size_t)G * 4);
    size_t zbytes = off;
    int* rowptr = (int*)A((size_t)(N + 1) * 4);
    int* part = (int*)A((size_t)64 * 4);
    float4* cefs = (float4*)A((size_t)Etot * 16);
    __half* xl16 = (__half*)A((size_t)N * 128 * 2);
    __half* xr16 = (__half*)A((size_t)N * 128 * 2);
    float* h0 = (float*)A((size_t)N * 128 * 4);
    float* h1 = (float*)A((size_t)N * 128 * 4);

    (void)hipMemsetAsync(d_ws, 0, zbytes, stream);

    dim3 B(TPB);
    k_count<<<(E + TPB - 1) / TPB, B, 0, stream>>>(dstA, cnt0, E);

    int ept = (N + 64 * TPB - 1) / (64 * TPB);
    if (ept < 4) ept = 4;
    int nb = (N + ept * TPB - 1) / (ept * TPB);
    k_scan_part<<<nb, B, 0, stream>>>(cnt0, part, N, ept);
    k_scan_top<<<1, 64, 0, stream>>>(part, rowptr, nb, N);
    k_scan_fin<<<nb, B, 0, stream>>>(cnt0, part, rowptr, N, ept);

    k_fill<<<(E + TPB - 1) / TPB, B, 0, stream>>>(srcA, dstA, ef, rowptr, fill, cefs, E);
    k_selfloop<<<(N + TPB - 1) / TPB, B, 0, stream>>>(rowptr, cnt0, cefs, N);

    float* houts[4] = {h0, h1, h0, h1};

    int nblk = (N + 31) / 32;
    int nblk64 = (N + 63) / 64;
    const float* hin = x;
    for (int l = 0; l < 4; ++l) {
        const float* wl  = (const float*)d_in[4 + l * 7 + 0];
        const float* bl  = (const float*)d_in[4 + l * 7 + 1];
        const float* wr  = (const float*)d_in[4 + l * 7 + 2];
        const float* br  = (const float*)d_in[4 + l * 7 + 3];
        const float* we  = (const float*)d_in[4 + l * 7 + 4];
        const float* att = (const float*)d_in[4 + l * 7 + 5];
        const float* cb  = (const float*)d_in[4 + l * 7 + 6];
        int H = (l == 3) ? 2 : 4;
        int C = (l == 0) ? 16 : 32;
        int HC = H * C;

        if (l == 0)      k_lin_s<5, 64>      <<<nblk, B, 0, stream>>>(hin, wl, bl, wr, br, xl16, xr16, N);
        else if (l == 1) k_lin_mfma<64, 128> <<<nblk64, B, 0, stream>>>(hin, wl, bl, wr, br, xl16, xr16, N);
        else if (l == 2) k_lin_mfma<128, 128><<<nblk64, B, 0, stream>>>(hin, wl, bl, wr, br, xl16, xr16, N);
        else             k_lin_mfma<128, 64> <<<nblk64, B, 0, stream>>>(hin, wl, bl, wr, br, xl16, xr16, N);

        int npw = 64 / (HC / 2);
        int waves = (N + npw - 1) / npw;
        int blocks = (waves + 3) / 4;
        if (H == 4 && C == 16)
            k_fused<4, 16><<<blocks, B, 0, stream>>>(rowptr, cefs, xl16, xr16,
                                                     we, att, cb, houts[l], N);
        else if (H == 4 && C == 32)
            k_fused<4, 32><<<blocks, B, 0, stream>>>(rowptr, cefs, xl16, xr16,
                                                     we, att, cb, houts[l], N);
        else
            k_fused<2, 32><<<blocks, B, 0, stream>>>(rowptr, cefs, xl16, xr16,
                                                     we, att, cb, houts[l], N);
        hin = houts[l];
    }

    k_pool<<<(N + 31) / 32, B, 0, stream>>>(hin, batch, psum, pcnt, N);
    k_final<<<(G * 32 + TPB - 1) / TPB, B, 0, stream>>>(psum, pcnt,
                                                        (const float*)d_in[32],
                                                        (const float*)d_in[33],
                                                        (float*)d_out, G);
}

// Round 15
// 392.685 us; speedup vs baseline: 1.5449x; 1.1006x over previous
//
#include <hip/hip_runtime.h>
#include <hip/hip_fp16.h>

#define TPB 256

typedef _Float16 hv2 __attribute__((ext_vector_type(2)));
typedef _Float16 hv4 __attribute__((ext_vector_type(4)));
typedef _Float16 f16x8 __attribute__((ext_vector_type(8)));
typedef float f32x4v __attribute__((ext_vector_type(4)));

// cvt_pkrtz returns an __fp16 vector; bit-cast to our _Float16 vector type
static __device__ __forceinline__ hv2 pkrtz(float a, float b) {
    auto t = __builtin_amdgcn_cvt_pkrtz(a, b);
    return __builtin_bit_cast(hv2, t);
}

static __device__ __forceinline__ hv4 pkrtz4(float a, float b, float c, float d) {
    uint2 tt = make_uint2(__builtin_bit_cast(unsigned int, pkrtz(a, b)),
                          __builtin_bit_cast(unsigned int, pkrtz(c, d)));
    return __builtin_bit_cast(hv4, tt);
}

// VALU DPP add: x += x[permuted lane] (row-local). CTRL is a compile-time imm.
template <int CTRL>
static __device__ __forceinline__ float dpp_add(float x) {
    int xi = __builtin_bit_cast(int, x);
    int yi = __builtin_amdgcn_update_dpp(0, xi, CTRL, 0xf, 0xf, true);
    return x + __builtin_bit_cast(float, yi);
}

// butterfly sum over SPAN lanes (SPAN = 4, 8 or 16; within a DPP row of 16)
template <int SPAN>
static __device__ __forceinline__ float dpp_reduce(float x) {
    x = dpp_add<0xB1>(x);                              // quad_perm xor1
    x = dpp_add<0x4E>(x);                              // quad_perm xor2
    if constexpr (SPAN >= 8)  x = dpp_add<0x141>(x);   // row_half_mirror == ^7
    if constexpr (SPAN >= 16) x = dpp_add<0x140>(x);   // row_mirror == ^15
    return x;
}

// ---------------- CSR build ----------------

__global__ void k_count(const int* __restrict__ dstA, int* __restrict__ cnt, int E) {
    int e = blockIdx.x * blockDim.x + threadIdx.x;
    if (e >= E) return;
    atomicAdd(&cnt[dstA[e]], 1);
}

// ---- 3-phase exclusive scan of (cnt[i]+1) ----
__global__ void k_scan_part(const int* __restrict__ cnt, int* __restrict__ part,
                            int N, int ept) {
    __shared__ int sm[TPB];
    int tid = threadIdx.x;
    int beg = (blockIdx.x * TPB + tid) * ept;
    int s = 0;
    for (int u = 0; u < ept; ++u) {
        int i = beg + u;
        if (i < N) s += cnt[i] + 1;
    }
    sm[tid] = s;
    __syncthreads();
    for (int st = TPB / 2; st; st >>= 1) {
        if (tid < st) sm[tid] += sm[tid + st];
        __syncthreads();
    }
    if (tid == 0) part[blockIdx.x] = sm[0];
}

__global__ void k_scan_top(int* __restrict__ part, int* __restrict__ rowptr,
                           int nb, int N) {
    int lane = threadIdx.x & 63;
    int orig = (lane < nb) ? part[lane] : 0;
    int v = orig;
    #pragma unroll
    for (int ofs = 1; ofs < 64; ofs <<= 1) {
        int t = __shfl_up(v, ofs);
        if (lane >= ofs) v += t;
    }
    if (lane < nb) part[lane] = v - orig;
    if (lane == 63) rowptr[N] = v;
}

__global__ void k_scan_fin(const int* __restrict__ cnt, const int* __restrict__ part,
                           int* __restrict__ rowptr, int N, int ept) {
    __shared__ int wsum[TPB / 64];
    int tid = threadIdx.x;
    int lane = tid & 63, wid = tid >> 6;
    int beg = (blockIdx.x * TPB + tid) * ept;
    int s = 0;
    for (int u = 0; u < ept; ++u) {
        int i = beg + u;
        if (i < N) s += cnt[i] + 1;
    }
    int v = s;
    #pragma unroll
    for (int ofs = 1; ofs < 64; ofs <<= 1) {
        int t = __shfl_up(v, ofs);
        if (lane >= ofs) v += t;
    }
    if (lane == 63) wsum[wid] = v;
    __syncthreads();
    int woff = 0;
    for (int k = 0; k < wid; ++k) woff += wsum[k];
    int acc = (v - s) + woff + part[blockIdx.x];
    for (int u = 0; u < ept; ++u) {
        int i = beg + u;
        if (i < N) { rowptr[i] = acc; acc += cnt[i] + 1; }
    }
}

// cefs[slot] = (f0, f1, f2, bitcast(src))
__global__ void k_fill(const int* __restrict__ srcA, const int* __restrict__ dstA,
                       const float* __restrict__ ef,
                       const int* __restrict__ rowptr, int* __restrict__ fill,
                       float4* __restrict__ cefs, int E) {
    int e = blockIdx.x * blockDim.x + threadIdx.x;
    if (e >= E) return;
    int d = dstA[e];
    int pos = atomicAdd(&fill[d], 1);
    int slot = rowptr[d] + pos;
    cefs[slot] = make_float4(ef[e * 3 + 0], ef[e * 3 + 1], ef[e * 3 + 2],
                             __int_as_float(srcA[e]));
}

__global__ void k_selfloop(const int* __restrict__ rowptr, const int* __restrict__ cnt,
                           float4* __restrict__ cefs, int N) {
    int i = blockIdx.x * blockDim.x + threadIdx.x;
    if (i >= N) return;
    int b = rowptr[i];
    int c = cnt[i];
    float s0 = 0.f, s1 = 0.f, s2 = 0.f;
    for (int s = b; s < b + c; ++s) {
        float4 q = cefs[s];
        s0 += q.x; s1 += q.y; s2 += q.z;
    }
    float inv = 1.0f / (float)max(c, 1);
    cefs[b + c] = make_float4(s0 * inv, s1 * inv, s2 * inv, __int_as_float(i));
}

// ---------------- layer-0 linear (F=5): simple register-tiled ----------------
template <int F, int HC>
__global__ void k_lin_s(const float* __restrict__ xin,
                        const float* __restrict__ wl, const float* __restrict__ bl,
                        const float* __restrict__ wr, const float* __restrict__ br,
                        __half* __restrict__ xl16, __half* __restrict__ xr16, int N) {
    constexpr int OPT = HC / 16;
    __shared__ float xs[32][F + 1];
    int n0 = blockIdx.x * 32;
    int tid = threadIdx.x;

    for (int idx = tid; idx < 32 * F; idx += TPB) {
        int n = idx / F, k = idx - n * F;
        int gn = n0 + n;
        xs[n][k] = (gn < N) ? xin[(size_t)gn * F + k] : 0.f;
    }
    __syncthreads();

    int og = tid & 31;
    int ng = tid >> 5;
    int o0 = og * OPT;
    bool isL = o0 < HC;
    int col = isL ? o0 : o0 - HC;
    const float* wp = isL ? wl : wr;
    const float* bp = isL ? bl : br;
    __half* outp = isL ? xl16 : xr16;

    float acc[4][OPT];
    #pragma unroll
    for (int j = 0; j < 4; ++j)
        #pragma unroll
        for (int m = 0; m < OPT; ++m) acc[j][m] = 0.f;

    #pragma unroll
    for (int k = 0; k < F; ++k) {
        float wv[OPT];
        #pragma unroll
        for (int m = 0; m < OPT; m += 4)
            *reinterpret_cast<float4*>(&wv[m]) =
                *reinterpret_cast<const float4*>(wp + (size_t)k * HC + col + m);
        #pragma unroll
        for (int j = 0; j < 4; ++j) {
            float xv = xs[ng * 4 + j][k];
            #pragma unroll
            for (int m = 0; m < OPT; ++m) acc[j][m] = fmaf(xv, wv[m], acc[j][m]);
        }
    }

    float bias[OPT];
    #pragma unroll
    for (int m = 0; m < OPT; ++m) bias[m] = bp[col + m];

    #pragma unroll
    for (int j = 0; j < 4; ++j) {
        int node = n0 + ng * 4 + j;
        if (node >= N) continue;
        #pragma unroll
        for (int m = 0; m < OPT; m += 2) {
            __half2 hv = __half2(__float2half(acc[j][m] + bias[m]),
                                 __float2half(acc[j][m + 1] + bias[m + 1]));
            *reinterpret_cast<__half2*>(outp + (size_t)node * HC + col + m) = hv;
        }
    }
}

// ---------------- big linear layers: MFMA fp16 GEMM ----------------
template <int F, int HC>
__global__ void k_lin_mfma(const float* __restrict__ xin,
                           const float* __restrict__ wl, const float* __restrict__ bl,
                           const float* __restrict__ wr, const float* __restrict__ br,
                           __half* __restrict__ xl16, __half* __restrict__ xr16, int N) {
    constexpr int W2 = 2 * HC;
    constexpr int NT = 64;
    constexpr int KC = 32;
    constexpr int CT = W2 / 16;
    constexpr int CTW = CT / 4;
    constexpr int C4 = W2 / 4;
    __shared__ _Float16 xs[NT][F + 8];
    __shared__ _Float16 wsT[W2][KC + 8];

    int n0 = blockIdx.x * NT;
    int tid = threadIdx.x;
    int lane = tid & 63;
    int wv = tid >> 6;
    int lane15 = lane & 15;
    int kb = (lane >> 4) * 8;

    for (int idx = tid * 4; idx < NT * F; idx += TPB * 4) {
        int n = idx / F, k = idx - n * F;
        int gn = n0 + n;
        float4 v = (gn < N) ? *reinterpret_cast<const float4*>(xin + (size_t)gn * F + k)
                            : make_float4(0.f, 0.f, 0.f, 0.f);
        unsigned int lo = __builtin_bit_cast(unsigned int, pkrtz(v.x, v.y));
        unsigned int hi = __builtin_bit_cast(unsigned int, pkrtz(v.z, v.w));
        *reinterpret_cast<uint2*>(&xs[n][k]) = make_uint2(lo, hi);
    }

    f32x4v acc[4][CTW];
    #pragma unroll
    for (int t = 0; t < CTW; ++t) {
        int col = (wv * CTW + t) * 16 + lane15;
        float bv = (col < HC) ? bl[col] : br[col - HC];
        #pragma unroll
        for (int tr = 0; tr < 4; ++tr) acc[tr][t] = (f32x4v){bv, bv, bv, bv};
    }

    for (int kc = 0; kc < F; kc += KC) {
        __syncthreads();
        for (int idx = tid; idx < (KC / 2) * C4; idx += TPB) {
            int k2 = idx / C4;
            int c = (idx - k2 * C4) * 4;
            int k = kc + k2 * 2;
            float4 r0, r1;
            if (c < HC) {
                r0 = *reinterpret_cast<const float4*>(wl + (size_t)k * HC + c);
                r1 = *reinterpret_cast<const float4*>(wl + (size_t)(k + 1) * HC + c);
            } else {
                int cc = c - HC;
                r0 = *reinterpret_cast<const float4*>(wr + (size_t)k * HC + cc);
                r1 = *reinterpret_cast<const float4*>(wr + (size_t)(k + 1) * HC + cc);
            }
            int kk = k2 * 2;
            *reinterpret_cast<unsigned int*>(&wsT[c + 0][kk]) = __builtin_bit_cast(unsigned int, pkrtz(r0.x, r1.x));
            *reinterpret_cast<unsigned int*>(&wsT[c + 1][kk]) = __builtin_bit_cast(unsigned int, pkrtz(r0.y, r1.y));
            *reinterpret_cast<unsigned int*>(&wsT[c + 2][kk]) = __builtin_bit_cast(unsigned int, pkrtz(r0.z, r1.z));
            *reinterpret_cast<unsigned int*>(&wsT[c + 3][kk]) = __builtin_bit_cast(unsigned int, pkrtz(r0.w, r1.w));
        }
        __syncthreads();

        f16x8 a[4];
        #pragma unroll
        for (int tr = 0; tr < 4; ++tr)
            a[tr] = *reinterpret_cast<const f16x8*>(&xs[tr * 16 + lane15][kc + kb]);
        #pragma unroll
        for (int t = 0; t < CTW; ++t) {
            int col = (wv * CTW + t) * 16 + lane15;
            f16x8 bfr = *reinterpret_cast<const f16x8*>(&wsT[col][kb]);
            #pragma unroll
            for (int tr = 0; tr < 4; ++tr)
                acc[tr][t] = __builtin_amdgcn_mfma_f32_16x16x32_f16(a[tr], bfr, acc[tr][t], 0, 0, 0);
        }
    }

    #pragma unroll
    for (int t = 0; t < CTW; ++t) {
        int col = (wv * CTW + t) * 16 + lane15;
        bool isL = col < HC;
        __half* outp = isL ? xl16 : xr16;
        int c = isL ? col : col - HC;
        #pragma unroll
        for (int tr = 0; tr < 4; ++tr) {
            #pragma unroll
            for (int j = 0; j < 4; ++j) {
                int node = n0 + tr * 16 + (lane >> 4) * 4 + j;
                if (node < N) outp[(size_t)node * HC + c] = __float2half(acc[tr][t][j]);
            }
        }
    }
}

// ---------------- fused GATv2 attention + aggregation ----------------
// 4 channels/lane: wave carries NPW=256/HC nodes -> NPW edges retired per
// iteration with one instruction stream. Packed-f16 math + DPP reduce.
template <int H, int C>
__global__ void k_fused(const int* __restrict__ rowptr,
                        const float4* __restrict__ cefs,
                        const __half* __restrict__ xl16, const __half* __restrict__ xr16,
                        const float* __restrict__ we, const float* __restrict__ att,
                        const float* __restrict__ cb, float* __restrict__ hout, int N) {
    constexpr int HC = H * C;
    constexpr int PAIRS = HC / 4;   // lanes per node (32 or 16)
    constexpr int NPW = 64 / PAIRS; // nodes per wave (2 or 4)
    constexpr int SPAN = C / 4;     // lanes per head (8 or 4)
    const _Float16* xl = reinterpret_cast<const _Float16*>(xl16);
    int wave = (blockIdx.x * blockDim.x + threadIdx.x) >> 6;
    int lane = threadIdx.x & 63;
    int g = lane / PAIRS;
    int p = lane % PAIRS;
    int node = wave * NPW + g;
    bool act = node < N;

    int o0 = 4 * p;
    float xr0 = 0.f, xr1 = 0.f, xr2 = 0.f, xr3 = 0.f;
    int b = 0, len = 0;
    if (act) {
        hv4 xr4 = *reinterpret_cast<const hv4*>(
            reinterpret_cast<const _Float16*>(xr16) + (size_t)node * HC + o0);
        xr0 = (float)xr4[0]; xr1 = (float)xr4[1];
        xr2 = (float)xr4[2]; xr3 = (float)xr4[3];
        b = rowptr[node];
        len = rowptr[node + 1] - b;
    }
    float w0a = we[o0 + 0], w0b = we[HC + o0 + 0], w0c = we[2 * HC + o0 + 0];
    float w1a = we[o0 + 1], w1b = we[HC + o0 + 1], w1c = we[2 * HC + o0 + 1];
    float w2a = we[o0 + 2], w2b = we[HC + o0 + 2], w2c = we[2 * HC + o0 + 2];
    float w3a = we[o0 + 3], w3b = we[HC + o0 + 3], w3c = we[2 * HC + o0 + 3];
    const float LOG2E = 1.44269504088896340736f;
    float at0f = att[o0 + 0] * LOG2E, at1f = att[o0 + 1] * LOG2E;
    float at2f = att[o0 + 2] * LOG2E, at3f = att[o0 + 3] * LOG2E;
    const hv4 k02 = {(_Float16)0.2f, (_Float16)0.2f, (_Float16)0.2f, (_Float16)0.2f};

    float m_run = -1e30f, den = 0.f;
    float acc0 = 0.f, acc1 = 0.f, acc2 = 0.f, acc3 = 0.f;

    int nk = (len + 3) >> 2;
    for (int kb = 0; kb < nk; ++kb) {
        int k0 = kb * 4;
        float L[4];
        hv4 xh[4];
        #pragma unroll
        for (int u = 0; u < 4; ++u) {
            int kk = k0 + u;
            bool v = kk < len;
            int s = b + (v ? kk : 0);
            float4 q = cefs[s];
            int src = __float_as_int(q.w);
            hv4 x4 = *reinterpret_cast<const hv4*>(xl + (size_t)src * HC + o0);
            float t0 = fmaf(q.z, w0c, fmaf(q.y, w0b, fmaf(q.x, w0a, xr0)));
            float t1 = fmaf(q.z, w1c, fmaf(q.y, w1b, fmaf(q.x, w1a, xr1)));
            float t2 = fmaf(q.z, w2c, fmaf(q.y, w2b, fmaf(q.x, w2a, xr2)));
            float t3 = fmaf(q.z, w3c, fmaf(q.y, w3b, fmaf(q.x, w3a, xr3)));
            hv4 s4 = x4 + pkrtz4(t0, t1, t2, t3);
            hv4 lr = __builtin_elementwise_max(s4, s4 * k02);  // leaky-relu
            float partial = fmaf((float)lr[0], at0f, fmaf((float)lr[1], at1f,
                            fmaf((float)lr[2], at2f, (float)lr[3] * at3f)));
            partial = dpp_reduce<SPAN>(partial);   // VALU DPP butterfly
            L[u] = v ? partial : -1e30f;
            xh[u] = x4;
        }
        float Lm = fmaxf(fmaxf(L[0], L[1]), fmaxf(L[2], L[3]));
        float nm = fmaxf(m_run, Lm);
        float sc = __builtin_amdgcn_exp2f(m_run - nm);
        float p0 = __builtin_amdgcn_exp2f(L[0] - nm);
        float p1 = __builtin_amdgcn_exp2f(L[1] - nm);
        float p2 = __builtin_amdgcn_exp2f(L[2] - nm);
        float p3 = __builtin_amdgcn_exp2f(L[3] - nm);
        den = den * sc + ((p0 + p1) + (p2 + p3));
        acc0 = fmaf(acc0, sc, fmaf(p0, (float)xh[0][0], fmaf(p1, (float)xh[1][0],
                    fmaf(p2, (float)xh[2][0], p3 * (float)xh[3][0]))));
        acc1 = fmaf(acc1, sc, fmaf(p0, (float)xh[0][1], fmaf(p1, (float)xh[1][1],
                    fmaf(p2, (float)xh[2][1], p3 * (float)xh[3][1]))));
        acc2 = fmaf(acc2, sc, fmaf(p0, (float)xh[0][2], fmaf(p1, (float)xh[1][2],
                    fmaf(p2, (float)xh[2][2], p3 * (float)xh[3][2]))));
        acc3 = fmaf(acc3, sc, fmaf(p0, (float)xh[0][3], fmaf(p1, (float)xh[1][3],
                    fmaf(p2, (float)xh[2][3], p3 * (float)xh[3][3]))));
        m_run = nm;
    }

    if (act) {
        float inv = 1.0f / den;  // self-loop guarantees den > 0
        float4 r = make_float4(fmaxf(acc0 * inv + cb[o0 + 0], 0.f),
                               fmaxf(acc1 * inv + cb[o0 + 1], 0.f),
                               fmaxf(acc2 * inv + cb[o0 + 2], 0.f),
                               fmaxf(acc3 * inv + cb[o0 + 3], 0.f));
        *reinterpret_cast<float4*>(hout + (size_t)node * HC + o0) = r;
    }
}

// ---------------- pooling + final linear ----------------
__global__ void k_pool(const float* __restrict__ h, const int* __restrict__ batch,
                       float* __restrict__ psum, int* __restrict__ pcnt, int N) {
    int o = threadIdx.x & 63;
    int j = threadIdx.x >> 6;
    int nb = blockIdx.x * 32;
    float acc = 0.f;
    int gcur = -1, cntacc = 0;
    for (int jj = j; jj < 32; jj += 4) {
        int node = nb + jj;
        if (node >= N) break;
        int g = batch[node];
        if (g != gcur) {
            if (gcur >= 0) {
                atomicAdd(&psum[gcur * 64 + o], acc);
                if (o == 0) atomicAdd(&pcnt[gcur], cntacc);
            }
            gcur = g; acc = 0.f; cntacc = 0;
        }
        acc += h[(size_t)node * 64 + o];
        ++cntacc;
    }
    if (gcur >= 0) {
        atomicAdd(&psum[gcur * 64 + o], acc);
        if (o == 0) atomicAdd(&pcnt[gcur], cntacc);
    }
}

__global__ void k_final(const float* __restrict__ psum, const int* __restrict__ pcnt,
                        const float* __restrict__ wlin, const float* __restrict__ blin,
                        float* __restrict__ out, int G) {
    int t = blockIdx.x * blockDim.x + threadIdx.x;
    if (t >= G * 32) return;
    int g = t / 32, j = t % 32;
    float acc = 0.f;
    for (int k = 0; k < 64; ++k) acc = fmaf(psum[g * 64 + k], wlin[k * 32 + j], acc);
    float inv = 1.0f / (float)max(pcnt[g], 1);
    out[t] = acc * inv + blin[j];
}

// ---------------- host ----------------

extern "C" void kernel_launch(void* const* d_in, const int* in_sizes, int n_in,
                              void* d_out, int out_size, void* d_ws, size_t ws_size,
                              hipStream_t stream) {
    const float* x = (const float*)d_in[0];
    const int* ei = (const int*)d_in[1];
    const float* ef = (const float*)d_in[2];
    const int* batch = (const int*)d_in[3];

    int N = in_sizes[0] / 5;
    int E = in_sizes[1] / 2;
    int G = out_size / 32;
    int Etot = E + N;
    const int* srcA = ei;
    const int* dstA = ei + E;

    char* w = (char*)d_ws;
    size_t off = 0;
    auto A = [&](size_t bytes) -> void* {
        void* p = w + off;
        off = (off + bytes + 255) & ~(size_t)255;
        return p;
    };
    // zero-init region: cnt0, fill, psum, pcnt
    int* cnt0 = (int*)A((size_t)N * 4);
    int* fill = (int*)A((size_t)N * 4);
    float* psum = (float*)A((size_t)G * 64 * 4);
    int* pcnt = (int*)A((size_t)G * 4);
    size_t zbytes = off;
    int* rowptr = (int*)A((size_t)(N + 1) * 4);
    int* part = (int*)A((size_t)64 * 4);
    float4* cefs = (float4*)A((size_t)Etot * 16);
    __half* xl16 = (__half*)A((size_t)N * 128 * 2);
    __half* xr16 = (__half*)A((size_t)N * 128 * 2);
    float* h0 = (float*)A((size_t)N * 128 * 4);
    float* h1 = (float*)A((size_t)N * 128 * 4);

    (void)hipMemsetAsync(d_ws, 0, zbytes, stream);

    dim3 B(TPB);
    k_count<<<(E + TPB - 1) / TPB, B, 0, stream>>>(dstA, cnt0, E);

    int ept = (N + 64 * TPB - 1) / (64 * TPB);
    if (ept < 4) ept = 4;
    int nb = (N + ept * TPB - 1) / (ept * TPB);
    k_scan_part<<<nb, B, 0, stream>>>(cnt0, part, N, ept);
    k_scan_top<<<1, 64, 0, stream>>>(part, rowptr, nb, N);
    k_scan_fin<<<nb, B, 0, stream>>>(cnt0, part, rowptr, N, ept);

    k_fill<<<(E + TPB - 1) / TPB, B, 0, stream>>>(srcA, dstA, ef, rowptr, fill, cefs, E);
    k_selfloop<<<(N + TPB - 1) / TPB, B, 0, stream>>>(rowptr, cnt0, cefs, N);

    float* houts[4] = {h0, h1, h0, h1};

    int nblk = (N + 31) / 32;
    int nblk64 = (N + 63) / 64;
    const float* hin = x;
    for (int l = 0; l < 4; ++l) {
        const float* wl  = (const float*)d_in[4 + l * 7 + 0];
        const float* bl  = (const float*)d_in[4 + l * 7 + 1];
        const float* wr  = (const float*)d_in[4 + l * 7 + 2];
        const float* br  = (const float*)d_in[4 + l * 7 + 3];
        const float* we  = (const float*)d_in[4 + l * 7 + 4];
        const float* att = (const float*)d_in[4 + l * 7 + 5];
        const float* cb  = (const float*)d_in[4 + l * 7 + 6];
        int H = (l == 3) ? 2 : 4;
        int C = (l == 0) ? 16 : 32;
        int HC = H * C;

        if (l == 0)      k_lin_s<5, 64>      <<<nblk, B, 0, stream>>>(hin, wl, bl, wr, br, xl16, xr16, N);
        else if (l == 1) k_lin_mfma<64, 128> <<<nblk64, B, 0, stream>>>(hin, wl, bl, wr, br, xl16, xr16, N);
        else if (l == 2) k_lin_mfma<128, 128><<<nblk64, B, 0, stream>>>(hin, wl, bl, wr, br, xl16, xr16, N);
        else             k_lin_mfma<128, 64> <<<nblk64, B, 0, stream>>>(hin, wl, bl, wr, br, xl16, xr16, N);

        int npw = 256 / HC;  // nodes per wave at 4 channels/lane
        long long waves = ((long long)N + npw - 1) / npw;
        int blocks = (int)((waves + 3) / 4);
        if (H == 4 && C == 16)
            k_fused<4, 16><<<blocks, B, 0, stream>>>(rowptr, cefs, xl16, xr16,
                                                     we, att, cb, houts[l], N);
        else if (H == 4 && C == 32)
            k_fused<4, 32><<<blocks, B, 0, stream>>>(rowptr, cefs, xl16, xr16,
                                                     we, att, cb, houts[l], N);
        else
            k_fused<2, 32><<<blocks, B, 0, stream>>>(rowptr, cefs, xl16, xr16,
                                                     we, att, cb, houts[l], N);
        hin = houts[l];
    }

    k_pool<<<(N + 31) / 32, B, 0, stream>>>(hin, batch, psum, pcnt, N);
    k_final<<<(G * 32 + TPB - 1) / TPB, B, 0, stream>>>(psum, pcnt,
                                                        (const float*)d_in[32],
                                                        (const float*)d_in[33],
                                                        (float*)d_out, G);
}